// Round 1
// baseline (1415.650 us; speedup 1.0000x reference)
//
#include <hip/hip_runtime.h>

// ---------------------------------------------------------------------------
// GCN block: 3 x (GCNConv -> ReLU -> global_mean_pool)
// Structure per launch:
//   1. init (deg=1 self-loop, zero cnt/counts/out)
//   2. deg + per-node in-degree histogram (atomics over E)
//   3. dinv = rsqrt(deg); per-graph node counts
//   4. exclusive scan of in-degree -> CSR ptr (single block, shuffle scan)
//   5. CSR fill: (src, norm) pairs bucketed by destination node
//   6. per layer: fp32 GEMM (h @ W) -> gather-aggregate (+self loop)
//      -> +bias -> ReLU -> pool-accumulate (atomics into d_out)
//   7. divide pooled sums by counts
// ---------------------------------------------------------------------------

__global__ void k_init(float* __restrict__ deg, int* __restrict__ cnt,
                       float* __restrict__ counts, float* __restrict__ out,
                       int N, int G, int OUT) {
    int i = blockIdx.x * blockDim.x + threadIdx.x;
    if (i < N) { deg[i] = 1.0f; cnt[i] = 0; }   // self-loop weight 1
    if (i < G) counts[i] = 0.f;
    if (i < OUT) out[i] = 0.f;
}

__global__ void k_deg_cnt(const int* __restrict__ ei, const float* __restrict__ ew,
                          float* __restrict__ deg, int* __restrict__ cnt, int E) {
    int e = blockIdx.x * blockDim.x + threadIdx.x;
    if (e >= E) return;
    int c = ei[E + e];              // col = target node
    atomicAdd(&deg[c], ew[e]);
    atomicAdd(&cnt[c], 1);
}

__global__ void k_dinv(float* __restrict__ deg, const int* __restrict__ batch,
                       float* __restrict__ counts, int N) {
    int i = blockIdx.x * blockDim.x + threadIdx.x;
    if (i >= N) return;
    float d = deg[i];
    deg[i] = (d > 0.f) ? rsqrtf(d) : 0.f;       // in-place deg -> dinv
    atomicAdd(&counts[batch[i]], 1.0f);
}

// Single-block exclusive scan (shuffle within wave, serial over 16 wave sums).
__global__ __launch_bounds__(1024) void k_scan(const int* __restrict__ cnt,
                                               int* __restrict__ ptr,
                                               int* __restrict__ cursor, int n) {
    __shared__ int wsum[16];
    int t = threadIdx.x;
    int lane = t & 63;
    int w = t >> 6;
    int carry = 0;
    for (int base = 0; base < n; base += 1024) {
        int i = base + t;
        int v = (i < n) ? cnt[i] : 0;
        int x = v;
#pragma unroll
        for (int off = 1; off < 64; off <<= 1) {
            int y = __shfl_up(x, off, 64);
            if (lane >= off) x += y;
        }
        if (lane == 63) wsum[w] = x;
        __syncthreads();
        int woff = 0, tot = 0;
#pragma unroll
        for (int q = 0; q < 16; q++) {
            int s = wsum[q];
            if (q < w) woff += s;
            tot += s;
        }
        int p = carry + woff + (x - v);
        if (i < n) { ptr[i] = p; cursor[i] = p; }
        carry += tot;
        __syncthreads();
    }
    if (t == 0) ptr[n] = carry;
}

__global__ void k_fill(const int* __restrict__ ei, const float* __restrict__ ew,
                       const float* __restrict__ dinv, int* __restrict__ cursor,
                       int2* __restrict__ csr, int E) {
    int e = blockIdx.x * blockDim.x + threadIdx.x;
    if (e >= E) return;
    int r = ei[e];
    int c = ei[E + e];
    float nv = dinv[r] * ew[e] * dinv[c];
    int pos = atomicAdd(&cursor[c], 1);
    int2 v; v.x = r; v.y = __float_as_int(nv);
    csr[pos] = v;
}

// hl = H @ W   (M x 128) @ (128 x 128), fp32 vector ALU.
// Block: 64 rows x 128 cols, 256 threads, each thread 8 rows x 4 cols.
// H tile staged in LDS (32 KB, contiguous copy); W read from global (L2-hot).
__global__ __launch_bounds__(256) void k_gemm(const float* __restrict__ H,
                                              const float* __restrict__ W,
                                              float* __restrict__ O, int M) {
    __shared__ float sH[64 * 128];
    int t = threadIdx.x;
    int rbase = blockIdx.x * 64;
    int nrows = M - rbase; if (nrows > 64) nrows = 64;
    const float4* H4 = (const float4*)(H + (size_t)rbase * 128);
    float4* sH4 = (float4*)sH;
    int nf4 = nrows * 32;
#pragma unroll
    for (int i = 0; i < 8; i++) {
        int idx = t + i * 256;
        float4 v = make_float4(0.f, 0.f, 0.f, 0.f);
        if (idx < nf4) v = H4[idx];
        sH4[idx] = v;
    }
    __syncthreads();
    int jc = t & 31;        // column group: cols 4*jc .. 4*jc+3
    int rg = t >> 5;        // row group:    rows 8*rg .. 8*rg+7
    const float4* W4 = (const float4*)W;
    float4 acc[8];
#pragma unroll
    for (int r = 0; r < 8; r++) acc[r] = make_float4(0.f, 0.f, 0.f, 0.f);
    const float* hrow = &sH[rg * 8 * 128];
#pragma unroll 4
    for (int k = 0; k < 128; k++) {
        float4 wv = W4[k * 32 + jc];
#pragma unroll
        for (int r = 0; r < 8; r++) {
            float hv = hrow[r * 128 + k];   // LDS broadcast (2 addrs / wave)
            acc[r].x += hv * wv.x;
            acc[r].y += hv * wv.y;
            acc[r].z += hv * wv.z;
            acc[r].w += hv * wv.w;
        }
    }
    float4* O4 = (float4*)O;
#pragma unroll
    for (int r = 0; r < 8; r++) {
        int row = rbase + rg * 8 + r;
        if (row < M) O4[(size_t)row * 32 + jc] = acc[r];
    }
}

// One wave per node: gather incoming messages, +bias, ReLU, write h_next,
// pool-accumulate into emb. Edge metadata loads are wave-uniform -> s_load.
__global__ __launch_bounds__(256) void k_agg(const float* __restrict__ HL,
                                             const int* __restrict__ ptr,
                                             const int2* __restrict__ csr,
                                             const float* __restrict__ dinv,
                                             const int* __restrict__ batch,
                                             const float* __restrict__ bias,
                                             float* __restrict__ Hout,
                                             float* __restrict__ emb, int M) {
    int wid = (int)((blockIdx.x * blockDim.x + threadIdx.x) >> 6);
    if (wid >= M) return;
    int node = __builtin_amdgcn_readfirstlane(wid);
    int lane = threadIdx.x & 63;
    const float2* HL2 = (const float2*)HL;
    float di = dinv[node];
    float sn = di * di;                          // self-loop norm
    float2 h0 = HL2[(size_t)node * 64 + lane];
    float ax = sn * h0.x, ay = sn * h0.y;
    int e0 = ptr[node], e1 = ptr[node + 1];
    for (int e = e0; e < e1; e++) {
        int2 en = csr[e];
        float nv = __int_as_float(en.y);
        float2 hv = HL2[(size_t)en.x * 64 + lane];
        ax += nv * hv.x;
        ay += nv * hv.y;
    }
    float2 bv = ((const float2*)bias)[lane];
    float rx = fmaxf(ax + bv.x, 0.f);
    float ry = fmaxf(ay + bv.y, 0.f);
    float2 rv; rv.x = rx; rv.y = ry;
    ((float2*)Hout)[(size_t)node * 64 + lane] = rv;
    int g = batch[node];
    atomicAdd(&emb[g * 128 + lane * 2], rx);
    atomicAdd(&emb[g * 128 + lane * 2 + 1], ry);
}

__global__ void k_div(float* __restrict__ out, const float* __restrict__ counts,
                      int G, int total) {
    int i = blockIdx.x * blockDim.x + threadIdx.x;
    if (i >= total) return;
    int g = (i >> 7) % G;                        // 128 features per graph
    out[i] = out[i] / fmaxf(counts[g], 1.0f);
}

extern "C" void kernel_launch(void* const* d_in, const int* in_sizes, int n_in,
                              void* d_out, int out_size, void* d_ws, size_t ws_size,
                              hipStream_t stream) {
    const float* x     = (const float*)d_in[0];
    const int*   ei    = (const int*)d_in[1];
    const float* ew    = (const float*)d_in[2];
    const int*   batch = (const int*)d_in[3];
    const float* Wt[3] = {(const float*)d_in[4], (const float*)d_in[6], (const float*)d_in[8]};
    const float* bt[3] = {(const float*)d_in[5], (const float*)d_in[7], (const float*)d_in[9]};
    float* out = (float*)d_out;

    const int D = 128;
    const int N = in_sizes[0] / D;       // 100000
    const int E = in_sizes[2];           // 1600000
    const int G = out_size / (3 * D);    // 256

    // workspace carve-up (256 B aligned)
    char* p = (char*)d_ws;
    auto alloc = [&](size_t bytes) {
        void* r = (void*)p;
        p += (bytes + 255) & ~(size_t)255;
        return r;
    };
    float* deg    = (float*)alloc((size_t)N * 4);          // becomes dinv
    int*   cnt    = (int*)alloc((size_t)N * 4);
    int*   cursor = (int*)alloc((size_t)N * 4);
    int*   ptr    = (int*)alloc((size_t)(N + 1) * 4);
    int2*  csr    = (int2*)alloc((size_t)E * 8);
    float* counts = (float*)alloc((size_t)G * 4);
    float* buf1   = (float*)alloc((size_t)N * D * 4);      // hl (projection)
    float* buf2   = (float*)alloc((size_t)N * D * 4);      // h_next

    k_init<<<(N + 255) / 256, 256, 0, stream>>>(deg, cnt, counts, out, N, G, out_size);
    k_deg_cnt<<<(E + 255) / 256, 256, 0, stream>>>(ei, ew, deg, cnt, E);
    k_dinv<<<(N + 255) / 256, 256, 0, stream>>>(deg, batch, counts, N);
    k_scan<<<1, 1024, 0, stream>>>(cnt, ptr, cursor, N);
    k_fill<<<(E + 255) / 256, 256, 0, stream>>>(ei, ew, deg, cursor, csr, E);

    const float* h = x;
    for (int l = 0; l < 3; l++) {
        k_gemm<<<(N + 63) / 64, 256, 0, stream>>>(h, Wt[l], buf1, N);
        k_agg<<<(N + 3) / 4, 256, 0, stream>>>(buf1, ptr, csr, deg, batch, bt[l],
                                               buf2, out + (size_t)l * G * D, N);
        h = buf2;
    }
    k_div<<<(out_size + 255) / 256, 256, 0, stream>>>(out, counts, G, out_size);
}

// Round 2
// 1298.754 us; speedup vs baseline: 1.0900x; 1.0900x over previous
//
#include <hip/hip_runtime.h>

// ---------------------------------------------------------------------------
// GCN block: 3 x (GCNConv -> ReLU -> global_mean_pool)
//   1. init (deg=1 self-loop, zero cnt/counts/out)
//   2. deg + per-node in-degree histogram (atomics over E)
//   3. dinv = rsqrt(deg); per-graph node counts
//   4. multi-block exclusive scan of in-degree -> CSR ptr
//   5. CSR fill: (src, norm) pairs bucketed by destination node
//   6. per layer: fp32 GEMM (h @ W) -> gather-aggregate (LDS-staged edge
//      metadata, unroll-4 gathers in flight) -> +bias -> ReLU -> pool
//   7. divide pooled sums by counts
// ---------------------------------------------------------------------------

__global__ void k_init(float* __restrict__ deg, int* __restrict__ cnt,
                       float* __restrict__ counts, float* __restrict__ out,
                       int N, int G, int OUT) {
    int i = blockIdx.x * blockDim.x + threadIdx.x;
    if (i < N) { deg[i] = 1.0f; cnt[i] = 0; }   // self-loop weight 1
    if (i < G) counts[i] = 0.f;
    if (i < OUT) out[i] = 0.f;
}

__global__ void k_deg_cnt(const int* __restrict__ ei, const float* __restrict__ ew,
                          float* __restrict__ deg, int* __restrict__ cnt, int E) {
    int e = blockIdx.x * blockDim.x + threadIdx.x;
    if (e >= E) return;
    int c = ei[E + e];              // col = target node
    atomicAdd(&deg[c], ew[e]);
    atomicAdd(&cnt[c], 1);
}

__global__ void k_dinv(float* __restrict__ deg, const int* __restrict__ batch,
                       float* __restrict__ counts, int N) {
    int i = blockIdx.x * blockDim.x + threadIdx.x;
    if (i >= N) return;
    float d = deg[i];
    deg[i] = (d > 0.f) ? rsqrtf(d) : 0.f;       // in-place deg -> dinv
    atomicAdd(&counts[batch[i]], 1.0f);
}

// --- multi-block exclusive scan: scan1 (per-block) -> scan2 (block sums) ---
__global__ __launch_bounds__(1024) void k_scan1(const int* __restrict__ cnt,
                                                int* __restrict__ pre,
                                                int* __restrict__ bsum, int n) {
    __shared__ int wsum[16];
    int t = threadIdx.x, lane = t & 63, w = t >> 6;
    int i = blockIdx.x * 1024 + t;
    int v = (i < n) ? cnt[i] : 0;
    int x = v;
#pragma unroll
    for (int off = 1; off < 64; off <<= 1) {
        int y = __shfl_up(x, off, 64);
        if (lane >= off) x += y;
    }
    if (lane == 63) wsum[w] = x;
    __syncthreads();
    int woff = 0, tot = 0;
#pragma unroll
    for (int q = 0; q < 16; q++) { int s = wsum[q]; if (q < w) woff += s; tot += s; }
    if (i < n) pre[i] = woff + x - v;
    if (t == 0) bsum[blockIdx.x] = tot;
}

// nb <= 128 (N <= 131072). Scans the block sums in place; ptr[n] = total.
__global__ __launch_bounds__(128) void k_scan2(int* __restrict__ bsum, int nb,
                                               int* __restrict__ ptrv, int n) {
    __shared__ int ws[2];
    int t = threadIdx.x, lane = t & 63, w = t >> 6;
    int v = (t < nb) ? bsum[t] : 0;
    int x = v;
#pragma unroll
    for (int off = 1; off < 64; off <<= 1) {
        int y = __shfl_up(x, off, 64);
        if (lane >= off) x += y;
    }
    if (lane == 63) ws[w] = x;
    __syncthreads();
    int woff = (w == 1) ? ws[0] : 0;
    int tot = ws[0] + ws[1];
    if (t < nb) bsum[t] = woff + x - v;
    if (t == 0) ptrv[n] = tot;
}

__global__ __launch_bounds__(1024) void k_scan3(const int* __restrict__ pre,
                                                const int* __restrict__ bsum,
                                                int* __restrict__ ptrv,
                                                int* __restrict__ cursor, int n) {
    int i = blockIdx.x * 1024 + threadIdx.x;
    if (i >= n) return;
    int p = pre[i] + bsum[blockIdx.x];
    ptrv[i] = p; cursor[i] = p;
}

__global__ void k_fill(const int* __restrict__ ei, const float* __restrict__ ew,
                       const float* __restrict__ dinv, int* __restrict__ cursor,
                       int2* __restrict__ csr, int E) {
    int e = blockIdx.x * blockDim.x + threadIdx.x;
    if (e >= E) return;
    int r = ei[e];
    int c = ei[E + e];
    float nv = dinv[r] * ew[e] * dinv[c];
    int pos = atomicAdd(&cursor[c], 1);
    int2 v; v.x = r; v.y = __float_as_int(nv);
    csr[pos] = v;
}

// hl = H @ W   (M x 128) @ (128 x 128), fp32 vector ALU.
__global__ __launch_bounds__(256) void k_gemm(const float* __restrict__ H,
                                              const float* __restrict__ W,
                                              float* __restrict__ O, int M) {
    __shared__ float sH[64 * 128];
    int t = threadIdx.x;
    int rbase = blockIdx.x * 64;
    int nrows = M - rbase; if (nrows > 64) nrows = 64;
    const float4* H4 = (const float4*)(H + (size_t)rbase * 128);
    float4* sH4 = (float4*)sH;
    int nf4 = nrows * 32;
#pragma unroll
    for (int i = 0; i < 8; i++) {
        int idx = t + i * 256;
        float4 v = make_float4(0.f, 0.f, 0.f, 0.f);
        if (idx < nf4) v = H4[idx];
        sH4[idx] = v;
    }
    __syncthreads();
    int jc = t & 31;        // column group: cols 4*jc .. 4*jc+3
    int rg = t >> 5;        // row group:    rows 8*rg .. 8*rg+7
    const float4* W4 = (const float4*)W;
    float4 acc[8];
#pragma unroll
    for (int r = 0; r < 8; r++) acc[r] = make_float4(0.f, 0.f, 0.f, 0.f);
    const float* hrow = &sH[rg * 8 * 128];
#pragma unroll 4
    for (int k = 0; k < 128; k++) {
        float4 wv = W4[k * 32 + jc];
#pragma unroll
        for (int r = 0; r < 8; r++) {
            float hv = hrow[r * 128 + k];   // LDS broadcast
            acc[r].x += hv * wv.x;
            acc[r].y += hv * wv.y;
            acc[r].z += hv * wv.z;
            acc[r].w += hv * wv.w;
        }
    }
    float4* O4 = (float4*)O;
#pragma unroll
    for (int r = 0; r < 8; r++) {
        int row = rbase + rg * 8 + r;
        if (row < M) O4[(size_t)row * 32 + jc] = acc[r];
    }
}

// One wave per node. Edge metadata (up to 64 entries) loaded coalesced into
// LDS by the wave's lanes, then the gather loop runs unroll-4 with only
// LDS-broadcast reads feeding independent 512B row gathers (4+ in flight).
__global__ __launch_bounds__(256) void k_agg(const float* __restrict__ HL,
                                             const int* __restrict__ ptr,
                                             const int2* __restrict__ csr,
                                             const float* __restrict__ dinv,
                                             const int* __restrict__ batch,
                                             const float* __restrict__ bias,
                                             float* __restrict__ Hout,
                                             float* __restrict__ emb, int M,
                                             int write_h) {
    __shared__ int2 sM[4 * 64];
    int node = (int)((blockIdx.x * blockDim.x + threadIdx.x) >> 6);
    if (node >= M) return;
    int lane = threadIdx.x & 63;
    int2* mbase = &sM[(threadIdx.x >> 6) * 64];
    int e0 = ptr[node], e1 = ptr[node + 1];
    int deg = e1 - e0;
    int nb = deg < 64 ? deg : 64;
    if (lane < nb) mbase[lane] = csr[e0 + lane];   // one coalesced load
    const float2* HL2 = (const float2*)HL;
    float di = dinv[node];
    float sn = di * di;                            // self-loop norm
    float2 h0 = HL2[(size_t)node * 64 + lane];
    float ax = sn * h0.x, ay = sn * h0.y;
    int j = 0;
    for (; j + 4 <= nb; j += 4) {
        int2 m0 = mbase[j + 0];
        int2 m1 = mbase[j + 1];
        int2 m2 = mbase[j + 2];
        int2 m3 = mbase[j + 3];
        float2 v0 = HL2[(size_t)m0.x * 64 + lane];
        float2 v1 = HL2[(size_t)m1.x * 64 + lane];
        float2 v2 = HL2[(size_t)m2.x * 64 + lane];
        float2 v3 = HL2[(size_t)m3.x * 64 + lane];
        ax += __int_as_float(m0.y) * v0.x; ay += __int_as_float(m0.y) * v0.y;
        ax += __int_as_float(m1.y) * v1.x; ay += __int_as_float(m1.y) * v1.y;
        ax += __int_as_float(m2.y) * v2.x; ay += __int_as_float(m2.y) * v2.y;
        ax += __int_as_float(m3.y) * v3.x; ay += __int_as_float(m3.y) * v3.y;
    }
    for (; j < nb; j++) {
        int2 m = mbase[j];
        float2 v = HL2[(size_t)m.x * 64 + lane];
        ax += __int_as_float(m.y) * v.x; ay += __int_as_float(m.y) * v.y;
    }
    for (int e = e0 + 64; e < e1; e++) {           // rare high-degree tail
        int2 m = csr[e];
        float2 v = HL2[(size_t)m.x * 64 + lane];
        ax += __int_as_float(m.y) * v.x; ay += __int_as_float(m.y) * v.y;
    }
    float2 bv = ((const float2*)bias)[lane];
    float rx = fmaxf(ax + bv.x, 0.f);
    float ry = fmaxf(ay + bv.y, 0.f);
    if (write_h) {
        float2 rv; rv.x = rx; rv.y = ry;
        ((float2*)Hout)[(size_t)node * 64 + lane] = rv;
    }
    int g = batch[node];
    atomicAdd(&emb[g * 128 + lane * 2], rx);
    atomicAdd(&emb[g * 128 + lane * 2 + 1], ry);
}

__global__ void k_div(float* __restrict__ out, const float* __restrict__ counts,
                      int G, int total) {
    int i = blockIdx.x * blockDim.x + threadIdx.x;
    if (i >= total) return;
    int g = (i >> 7) % G;                          // 128 features per graph
    out[i] = out[i] / fmaxf(counts[g], 1.0f);
}

extern "C" void kernel_launch(void* const* d_in, const int* in_sizes, int n_in,
                              void* d_out, int out_size, void* d_ws, size_t ws_size,
                              hipStream_t stream) {
    const float* x     = (const float*)d_in[0];
    const int*   ei    = (const int*)d_in[1];
    const float* ew    = (const float*)d_in[2];
    const int*   batch = (const int*)d_in[3];
    const float* Wt[3] = {(const float*)d_in[4], (const float*)d_in[6], (const float*)d_in[8]};
    const float* bt[3] = {(const float*)d_in[5], (const float*)d_in[7], (const float*)d_in[9]};
    float* out = (float*)d_out;

    const int D = 128;
    const int N = in_sizes[0] / D;       // 100000
    const int E = in_sizes[2];           // 1600000
    const int G = out_size / (3 * D);    // 256

    // workspace carve-up (256 B aligned)
    char* p = (char*)d_ws;
    auto alloc = [&](size_t bytes) {
        void* r = (void*)p;
        p += (bytes + 255) & ~(size_t)255;
        return r;
    };
    float* deg    = (float*)alloc((size_t)N * 4);          // becomes dinv
    int*   cnt    = (int*)alloc((size_t)N * 4);
    int*   cursor = (int*)alloc((size_t)N * 4);
    int*   ptr    = (int*)alloc((size_t)(N + 1) * 4);
    int*   pre    = (int*)alloc((size_t)N * 4);
    int*   bsum   = (int*)alloc((size_t)128 * 4);
    int2*  csr    = (int2*)alloc((size_t)E * 8);
    float* counts = (float*)alloc((size_t)G * 4);
    float* buf1   = (float*)alloc((size_t)N * D * 4);      // hl (projection)
    float* buf2   = (float*)alloc((size_t)N * D * 4);      // h_next

    int nb = (N + 1023) / 1024;

    k_init<<<(N + 255) / 256, 256, 0, stream>>>(deg, cnt, counts, out, N, G, out_size);
    k_deg_cnt<<<(E + 255) / 256, 256, 0, stream>>>(ei, ew, deg, cnt, E);
    k_dinv<<<(N + 255) / 256, 256, 0, stream>>>(deg, batch, counts, N);
    k_scan1<<<nb, 1024, 0, stream>>>(cnt, pre, bsum, N);
    k_scan2<<<1, 128, 0, stream>>>(bsum, nb, ptr, N);
    k_scan3<<<nb, 1024, 0, stream>>>(pre, bsum, ptr, cursor, N);
    k_fill<<<(E + 255) / 256, 256, 0, stream>>>(ei, ew, deg, cursor, csr, E);

    const float* h = x;
    for (int l = 0; l < 3; l++) {
        k_gemm<<<(N + 63) / 64, 256, 0, stream>>>(h, Wt[l], buf1, N);
        k_agg<<<(N + 3) / 4, 256, 0, stream>>>(buf1, ptr, csr, deg, batch, bt[l],
                                               buf2, out + (size_t)l * G * D, N,
                                               l < 2 ? 1 : 0);
        h = buf2;
    }
    k_div<<<(out_size + 255) / 256, 256, 0, stream>>>(out, counts, G, out_size);
}

// Round 3
// 1167.958 us; speedup vs baseline: 1.2121x; 1.1120x over previous
//
#include <hip/hip_runtime.h>

// ---------------------------------------------------------------------------
// GCN block: 3 x (GCNConv -> ReLU -> global_mean_pool)
//   1. init (deg=1 self-loop, zero cnt/counts/out)
//   2. deg + per-node in-degree histogram (atomics over E)
//   3. dinv = rsqrt(deg); per-graph node counts
//   4. multi-block exclusive scan of in-degree -> CSR ptr
//   5. CSR fill: (src, norm) pairs bucketed by destination node
//   6. per layer: fp32 GEMM (h @ W) -> bf16 hl -> gather-aggregate in fp32
//      (LDS-staged edge metadata, unroll-8) -> +bias -> ReLU -> pool
//   7. divide pooled sums by counts
// hl stored as packed bf16 (2/lane): halves gather bytes, fits LLC/L2 better.
// ---------------------------------------------------------------------------

__device__ inline unsigned pack_bf16x2(float a, float b) {
    unsigned ua = __float_as_uint(a);
    ua = (ua + 0x7FFFu + ((ua >> 16) & 1u)) >> 16;       // RNE
    unsigned ub = __float_as_uint(b);
    ub = (ub + 0x7FFFu + ((ub >> 16) & 1u)) >> 16;
    return ua | (ub << 16);
}
__device__ inline float bf_lo(unsigned u) { return __uint_as_float(u << 16); }
__device__ inline float bf_hi(unsigned u) { return __uint_as_float(u & 0xFFFF0000u); }

__global__ void k_init(float* __restrict__ deg, int* __restrict__ cnt,
                       float* __restrict__ counts, float* __restrict__ out,
                       int N, int G, int OUT) {
    int i = blockIdx.x * blockDim.x + threadIdx.x;
    if (i < N) { deg[i] = 1.0f; cnt[i] = 0; }   // self-loop weight 1
    if (i < G) counts[i] = 0.f;
    if (i < OUT) out[i] = 0.f;
}

__global__ void k_deg_cnt(const int* __restrict__ ei, const float* __restrict__ ew,
                          float* __restrict__ deg, int* __restrict__ cnt, int E) {
    int e = blockIdx.x * blockDim.x + threadIdx.x;
    if (e >= E) return;
    int c = ei[E + e];              // col = target node
    atomicAdd(&deg[c], ew[e]);
    atomicAdd(&cnt[c], 1);
}

__global__ void k_dinv(float* __restrict__ deg, const int* __restrict__ batch,
                       float* __restrict__ counts, int N) {
    int i = blockIdx.x * blockDim.x + threadIdx.x;
    if (i >= N) return;
    float d = deg[i];
    deg[i] = (d > 0.f) ? rsqrtf(d) : 0.f;       // in-place deg -> dinv
    atomicAdd(&counts[batch[i]], 1.0f);
}

// --- multi-block exclusive scan: scan1 (per-block) -> scan2 (block sums) ---
__global__ __launch_bounds__(1024) void k_scan1(const int* __restrict__ cnt,
                                                int* __restrict__ pre,
                                                int* __restrict__ bsum, int n) {
    __shared__ int wsum[16];
    int t = threadIdx.x, lane = t & 63, w = t >> 6;
    int i = blockIdx.x * 1024 + t;
    int v = (i < n) ? cnt[i] : 0;
    int x = v;
#pragma unroll
    for (int off = 1; off < 64; off <<= 1) {
        int y = __shfl_up(x, off, 64);
        if (lane >= off) x += y;
    }
    if (lane == 63) wsum[w] = x;
    __syncthreads();
    int woff = 0, tot = 0;
#pragma unroll
    for (int q = 0; q < 16; q++) { int s = wsum[q]; if (q < w) woff += s; tot += s; }
    if (i < n) pre[i] = woff + x - v;
    if (t == 0) bsum[blockIdx.x] = tot;
}

__global__ __launch_bounds__(128) void k_scan2(int* __restrict__ bsum, int nb,
                                               int* __restrict__ ptrv, int n) {
    __shared__ int ws[2];
    int t = threadIdx.x, lane = t & 63, w = t >> 6;
    int v = (t < nb) ? bsum[t] : 0;
    int x = v;
#pragma unroll
    for (int off = 1; off < 64; off <<= 1) {
        int y = __shfl_up(x, off, 64);
        if (lane >= off) x += y;
    }
    if (lane == 63) ws[w] = x;
    __syncthreads();
    int woff = (w == 1) ? ws[0] : 0;
    int tot = ws[0] + ws[1];
    if (t < nb) bsum[t] = woff + x - v;
    if (t == 0) ptrv[n] = tot;
}

__global__ __launch_bounds__(1024) void k_scan3(const int* __restrict__ pre,
                                                const int* __restrict__ bsum,
                                                int* __restrict__ ptrv,
                                                int* __restrict__ cursor, int n) {
    int i = blockIdx.x * 1024 + threadIdx.x;
    if (i >= n) return;
    int p = pre[i] + bsum[blockIdx.x];
    ptrv[i] = p; cursor[i] = p;
}

__global__ void k_fill(const int* __restrict__ ei, const float* __restrict__ ew,
                       const float* __restrict__ dinv, int* __restrict__ cursor,
                       int2* __restrict__ csr, int E) {
    int e = blockIdx.x * blockDim.x + threadIdx.x;
    if (e >= E) return;
    int r = ei[e];
    int c = ei[E + e];
    float nv = dinv[r] * ew[e] * dinv[c];
    int pos = atomicAdd(&cursor[c], 1);
    int2 v; v.x = r; v.y = __float_as_int(nv);
    csr[pos] = v;
}

// hl = H @ W   (M x 128) @ (128 x 128), fp32 vector ALU, bf16-packed output.
__global__ __launch_bounds__(256) void k_gemm(const float* __restrict__ H,
                                              const float* __restrict__ W,
                                              unsigned* __restrict__ O, int M) {
    __shared__ float sH[64 * 128];
    int t = threadIdx.x;
    int rbase = blockIdx.x * 64;
    int nrows = M - rbase; if (nrows > 64) nrows = 64;
    const float4* H4 = (const float4*)(H + (size_t)rbase * 128);
    float4* sH4 = (float4*)sH;
    int nf4 = nrows * 32;
#pragma unroll
    for (int i = 0; i < 8; i++) {
        int idx = t + i * 256;
        float4 v = make_float4(0.f, 0.f, 0.f, 0.f);
        if (idx < nf4) v = H4[idx];
        sH4[idx] = v;
    }
    __syncthreads();
    int jc = t & 31;        // column group: cols 4*jc .. 4*jc+3
    int rg = t >> 5;        // row group:    rows 8*rg .. 8*rg+7
    const float4* W4 = (const float4*)W;
    float4 acc[8];
#pragma unroll
    for (int r = 0; r < 8; r++) acc[r] = make_float4(0.f, 0.f, 0.f, 0.f);
    const float* hrow = &sH[rg * 8 * 128];
#pragma unroll 4
    for (int k = 0; k < 128; k++) {
        float4 wv = W4[k * 32 + jc];
#pragma unroll
        for (int r = 0; r < 8; r++) {
            float hv = hrow[r * 128 + k];   // LDS broadcast
            acc[r].x += hv * wv.x;
            acc[r].y += hv * wv.y;
            acc[r].z += hv * wv.z;
            acc[r].w += hv * wv.w;
        }
    }
    uint2* O2 = (uint2*)O;
#pragma unroll
    for (int r = 0; r < 8; r++) {
        int row = rbase + rg * 8 + r;
        if (row < M) {
            uint2 pv;
            pv.x = pack_bf16x2(acc[r].x, acc[r].y);
            pv.y = pack_bf16x2(acc[r].z, acc[r].w);
            O2[(size_t)row * 32 + jc] = pv;
        }
    }
}

// One wave per node; hl rows are 256 B (64 lanes x packed bf16x2).
// Edge metadata staged in LDS; gather loop unroll-8 (8 rows in flight).
__global__ __launch_bounds__(256) void k_agg(const unsigned* __restrict__ HL,
                                             const int* __restrict__ ptr,
                                             const int2* __restrict__ csr,
                                             const float* __restrict__ dinv,
                                             const int* __restrict__ batch,
                                             const float* __restrict__ bias,
                                             float* __restrict__ Hout,
                                             float* __restrict__ emb, int M,
                                             int write_h) {
    __shared__ int2 sM[4 * 64];
    int node = (int)((blockIdx.x * blockDim.x + threadIdx.x) >> 6);
    if (node >= M) return;
    int lane = threadIdx.x & 63;
    int2* mbase = &sM[(threadIdx.x >> 6) * 64];
    int e0 = ptr[node], e1 = ptr[node + 1];
    int deg = e1 - e0;
    int nb = deg < 64 ? deg : 64;
    if (lane < nb) mbase[lane] = csr[e0 + lane];   // one coalesced load
    float di = dinv[node];
    float sn = di * di;                            // self-loop norm
    unsigned u0 = HL[(size_t)node * 64 + lane];
    float ax = sn * bf_lo(u0), ay = sn * bf_hi(u0);
    int j = 0;
    for (; j + 8 <= nb; j += 8) {
        int2 m[8];
        unsigned u[8];
#pragma unroll
        for (int q = 0; q < 8; q++) m[q] = mbase[j + q];
#pragma unroll
        for (int q = 0; q < 8; q++) u[q] = HL[(size_t)m[q].x * 64 + lane];
#pragma unroll
        for (int q = 0; q < 8; q++) {
            float nv = __int_as_float(m[q].y);
            ax += nv * bf_lo(u[q]);
            ay += nv * bf_hi(u[q]);
        }
    }
    for (; j < nb; j++) {
        int2 m = mbase[j];
        unsigned u = HL[(size_t)m.x * 64 + lane];
        float nv = __int_as_float(m.y);
        ax += nv * bf_lo(u);
        ay += nv * bf_hi(u);
    }
    for (int e = e0 + 64; e < e1; e++) {           // rare high-degree tail
        int2 m = csr[e];
        unsigned u = HL[(size_t)m.x * 64 + lane];
        float nv = __int_as_float(m.y);
        ax += nv * bf_lo(u);
        ay += nv * bf_hi(u);
    }
    float2 bv = ((const float2*)bias)[lane];
    float rx = fmaxf(ax + bv.x, 0.f);
    float ry = fmaxf(ay + bv.y, 0.f);
    if (write_h) {
        float2 rv; rv.x = rx; rv.y = ry;
        ((float2*)Hout)[(size_t)node * 64 + lane] = rv;
    }
    int g = batch[node];
    atomicAdd(&emb[g * 128 + lane * 2], rx);
    atomicAdd(&emb[g * 128 + lane * 2 + 1], ry);
}

__global__ void k_div(float* __restrict__ out, const float* __restrict__ counts,
                      int G, int total) {
    int i = blockIdx.x * blockDim.x + threadIdx.x;
    if (i >= total) return;
    int g = (i >> 7) % G;                          // 128 features per graph
    out[i] = out[i] / fmaxf(counts[g], 1.0f);
}

extern "C" void kernel_launch(void* const* d_in, const int* in_sizes, int n_in,
                              void* d_out, int out_size, void* d_ws, size_t ws_size,
                              hipStream_t stream) {
    const float* x     = (const float*)d_in[0];
    const int*   ei    = (const int*)d_in[1];
    const float* ew    = (const float*)d_in[2];
    const int*   batch = (const int*)d_in[3];
    const float* Wt[3] = {(const float*)d_in[4], (const float*)d_in[6], (const float*)d_in[8]};
    const float* bt[3] = {(const float*)d_in[5], (const float*)d_in[7], (const float*)d_in[9]};
    float* out = (float*)d_out;

    const int D = 128;
    const int N = in_sizes[0] / D;       // 100000
    const int E = in_sizes[2];           // 1600000
    const int G = out_size / (3 * D);    // 256

    // workspace carve-up (256 B aligned)
    char* p = (char*)d_ws;
    auto alloc = [&](size_t bytes) {
        void* r = (void*)p;
        p += (bytes + 255) & ~(size_t)255;
        return r;
    };
    float*    deg    = (float*)alloc((size_t)N * 4);       // becomes dinv
    int*      cnt    = (int*)alloc((size_t)N * 4);
    int*      cursor = (int*)alloc((size_t)N * 4);
    int*      ptr    = (int*)alloc((size_t)(N + 1) * 4);
    int*      pre    = (int*)alloc((size_t)N * 4);
    int*      bsum   = (int*)alloc((size_t)128 * 4);
    int2*     csr    = (int2*)alloc((size_t)E * 8);
    float*    counts = (float*)alloc((size_t)G * 4);
    unsigned* buf1   = (unsigned*)alloc((size_t)N * 64 * 4);  // hl, bf16-packed
    float*    buf2   = (float*)alloc((size_t)N * D * 4);      // h_next (fp32)

    int nb = (N + 1023) / 1024;

    k_init<<<(N + 255) / 256, 256, 0, stream>>>(deg, cnt, counts, out, N, G, out_size);
    k_deg_cnt<<<(E + 255) / 256, 256, 0, stream>>>(ei, ew, deg, cnt, E);
    k_dinv<<<(N + 255) / 256, 256, 0, stream>>>(deg, batch, counts, N);
    k_scan1<<<nb, 1024, 0, stream>>>(cnt, pre, bsum, N);
    k_scan2<<<1, 128, 0, stream>>>(bsum, nb, ptr, N);
    k_scan3<<<nb, 1024, 0, stream>>>(pre, bsum, ptr, cursor, N);
    k_fill<<<(E + 255) / 256, 256, 0, stream>>>(ei, ew, deg, cursor, csr, E);

    const float* h = x;
    for (int l = 0; l < 3; l++) {
        k_gemm<<<(N + 63) / 64, 256, 0, stream>>>(h, Wt[l], buf1, N);
        k_agg<<<(N + 3) / 4, 256, 0, stream>>>(buf1, ptr, csr, deg, batch, bt[l],
                                               buf2, out + (size_t)l * G * D, N,
                                               l < 2 ? 1 : 0);
        h = buf2;
    }
    k_div<<<(out_size + 255) / 256, 256, 0, stream>>>(out, counts, G, out_size);
}

// Round 4
// 764.877 us; speedup vs baseline: 1.8508x; 1.5270x over previous
//
#include <hip/hip_runtime.h>

// ---------------------------------------------------------------------------
// GCN block: 3 x (GCNConv -> ReLU -> global_mean_pool)
//   setup: deg/cnt histogram -> dinv -> scan -> CSR fill; graph boundaries
//          via binary search on sorted batch (NO atomics for counts).
//   per layer: GEMM (fp32 compute, bf16-packed out; bf16 in for layers 2/3)
//              -> gather-aggregate fp32 (LDS edge metadata, unroll-8)
//              -> h stored bf16 -> segment pool per graph (no atomics).
// ---------------------------------------------------------------------------

__device__ inline unsigned pack_bf16x2(float a, float b) {
    unsigned ua = __float_as_uint(a);
    ua = (ua + 0x7FFFu + ((ua >> 16) & 1u)) >> 16;       // RNE
    unsigned ub = __float_as_uint(b);
    ub = (ub + 0x7FFFu + ((ub >> 16) & 1u)) >> 16;
    return ua | (ub << 16);
}
__device__ inline float bf_lo(unsigned u) { return __uint_as_float(u << 16); }
__device__ inline float bf_hi(unsigned u) { return __uint_as_float(u & 0xFFFF0000u); }

__global__ void k_init(float* __restrict__ deg, int* __restrict__ cnt, int N) {
    int i = blockIdx.x * blockDim.x + threadIdx.x;
    if (i < N) { deg[i] = 1.0f; cnt[i] = 0; }   // self-loop weight 1
}

__global__ void k_deg_cnt(const int* __restrict__ ei, const float* __restrict__ ew,
                          float* __restrict__ deg, int* __restrict__ cnt, int E) {
    int e = blockIdx.x * blockDim.x + threadIdx.x;
    if (e >= E) return;
    int c = ei[E + e];              // col = target node
    atomicAdd(&deg[c], ew[e]);
    atomicAdd(&cnt[c], 1);
}

__global__ void k_dinv(float* __restrict__ deg, int N) {
    int i = blockIdx.x * blockDim.x + threadIdx.x;
    if (i >= N) return;
    float d = deg[i];
    deg[i] = (d > 0.f) ? rsqrtf(d) : 0.f;       // in-place deg -> dinv
}

// gb[g] = lower_bound(batch, g) for g in [0, G]; counts[g] = gb[g+1]-gb[g].
__global__ void k_bounds(const int* __restrict__ batch, int* __restrict__ gb,
                         int N, int G) {
    int t = blockIdx.x * blockDim.x + threadIdx.x;
    if (t > G) return;
    int lo = 0, hi = N;
    while (lo < hi) { int mid = (lo + hi) >> 1; if (batch[mid] < t) lo = mid + 1; else hi = mid; }
    gb[t] = lo;
}

// --- multi-block exclusive scan: scan1 (per-block) -> scan2 (block sums) ---
__global__ __launch_bounds__(1024) void k_scan1(const int* __restrict__ cnt,
                                                int* __restrict__ pre,
                                                int* __restrict__ bsum, int n) {
    __shared__ int wsum[16];
    int t = threadIdx.x, lane = t & 63, w = t >> 6;
    int i = blockIdx.x * 1024 + t;
    int v = (i < n) ? cnt[i] : 0;
    int x = v;
#pragma unroll
    for (int off = 1; off < 64; off <<= 1) {
        int y = __shfl_up(x, off, 64);
        if (lane >= off) x += y;
    }
    if (lane == 63) wsum[w] = x;
    __syncthreads();
    int woff = 0, tot = 0;
#pragma unroll
    for (int q = 0; q < 16; q++) { int s = wsum[q]; if (q < w) woff += s; tot += s; }
    if (i < n) pre[i] = woff + x - v;
    if (t == 0) bsum[blockIdx.x] = tot;
}

__global__ __launch_bounds__(128) void k_scan2(int* __restrict__ bsum, int nb,
                                               int* __restrict__ ptrv, int n) {
    __shared__ int ws[2];
    int t = threadIdx.x, lane = t & 63, w = t >> 6;
    int v = (t < nb) ? bsum[t] : 0;
    int x = v;
#pragma unroll
    for (int off = 1; off < 64; off <<= 1) {
        int y = __shfl_up(x, off, 64);
        if (lane >= off) x += y;
    }
    if (lane == 63) ws[w] = x;
    __syncthreads();
    int woff = (w == 1) ? ws[0] : 0;
    int tot = ws[0] + ws[1];
    if (t < nb) bsum[t] = woff + x - v;
    if (t == 0) ptrv[n] = tot;
}

__global__ __launch_bounds__(1024) void k_scan3(const int* __restrict__ pre,
                                                const int* __restrict__ bsum,
                                                int* __restrict__ ptrv,
                                                int* __restrict__ cursor, int n) {
    int i = blockIdx.x * 1024 + threadIdx.x;
    if (i >= n) return;
    int p = pre[i] + bsum[blockIdx.x];
    ptrv[i] = p; cursor[i] = p;
}

__global__ void k_fill(const int* __restrict__ ei, const float* __restrict__ ew,
                       const float* __restrict__ dinv, int* __restrict__ cursor,
                       int2* __restrict__ csr, int E) {
    int e = blockIdx.x * blockDim.x + threadIdx.x;
    if (e >= E) return;
    int r = ei[e];
    int c = ei[E + e];
    float nv = dinv[r] * ew[e] * dinv[c];
    int pos = atomicAdd(&cursor[c], 1);
    int2 v; v.x = r; v.y = __float_as_int(nv);
    csr[pos] = v;
}

// hl = H @ W  (M x 128) @ (128 x 128), fp32 vector ALU, bf16-packed output.
// BF16IN: input rows are packed bf16 (N x 64 uint); else fp32 (N x 128).
template <bool BF16IN>
__global__ __launch_bounds__(256) void k_gemm(const void* __restrict__ Hin,
                                              const float* __restrict__ W,
                                              unsigned* __restrict__ O, int M) {
    __shared__ float sH[64 * 128];
    int t = threadIdx.x;
    int rbase = blockIdx.x * 64;
    int nrows = M - rbase; if (nrows > 64) nrows = 64;
    float4* sH4 = (float4*)sH;
    int nf = nrows * 32;                // 32 16B-groups per row either way
    if (BF16IN) {
        const uint2* H2 = (const uint2*)Hin + (size_t)rbase * 32;
#pragma unroll
        for (int i = 0; i < 8; i++) {
            int idx = t + i * 256;
            float4 f = make_float4(0.f, 0.f, 0.f, 0.f);
            if (idx < nf) {
                uint2 v = H2[idx];
                f.x = bf_lo(v.x); f.y = bf_hi(v.x);
                f.z = bf_lo(v.y); f.w = bf_hi(v.y);
            }
            sH4[idx] = f;
        }
    } else {
        const float4* H4 = (const float4*)Hin + (size_t)rbase * 32;
#pragma unroll
        for (int i = 0; i < 8; i++) {
            int idx = t + i * 256;
            float4 v = make_float4(0.f, 0.f, 0.f, 0.f);
            if (idx < nf) v = H4[idx];
            sH4[idx] = v;
        }
    }
    __syncthreads();
    int jc = t & 31;        // column group: cols 4*jc .. 4*jc+3
    int rg = t >> 5;        // row group:    rows 8*rg .. 8*rg+7
    const float4* W4 = (const float4*)W;
    float4 acc[8];
#pragma unroll
    for (int r = 0; r < 8; r++) acc[r] = make_float4(0.f, 0.f, 0.f, 0.f);
    const float* hrow = &sH[rg * 8 * 128];
#pragma unroll 4
    for (int k = 0; k < 128; k++) {
        float4 wv = W4[k * 32 + jc];
#pragma unroll
        for (int r = 0; r < 8; r++) {
            float hv = hrow[r * 128 + k];   // LDS broadcast
            acc[r].x += hv * wv.x;
            acc[r].y += hv * wv.y;
            acc[r].z += hv * wv.z;
            acc[r].w += hv * wv.w;
        }
    }
    uint2* O2 = (uint2*)O;
#pragma unroll
    for (int r = 0; r < 8; r++) {
        int row = rbase + rg * 8 + r;
        if (row < M) {
            uint2 pv;
            pv.x = pack_bf16x2(acc[r].x, acc[r].y);
            pv.y = pack_bf16x2(acc[r].z, acc[r].w);
            O2[(size_t)row * 32 + jc] = pv;
        }
    }
}

// One wave per node; hl rows 256 B (64 lanes x packed bf16x2). Edge metadata
// staged in LDS; unroll-8 gathers in flight. h written packed bf16; pooling
// is a separate no-atomics kernel.
__global__ __launch_bounds__(256) void k_agg(const unsigned* __restrict__ HL,
                                             const int* __restrict__ ptr,
                                             const int2* __restrict__ csr,
                                             const float* __restrict__ dinv,
                                             const float* __restrict__ bias,
                                             unsigned* __restrict__ Hout, int M) {
    __shared__ int2 sM[4 * 64];
    int node = (int)((blockIdx.x * blockDim.x + threadIdx.x) >> 6);
    if (node >= M) return;
    int lane = threadIdx.x & 63;
    int2* mbase = &sM[(threadIdx.x >> 6) * 64];
    int e0 = ptr[node], e1 = ptr[node + 1];
    int deg = e1 - e0;
    int nb = deg < 64 ? deg : 64;
    if (lane < nb) mbase[lane] = csr[e0 + lane];   // one coalesced load
    float di = dinv[node];
    float sn = di * di;                            // self-loop norm
    unsigned u0 = HL[(size_t)node * 64 + lane];
    float ax = sn * bf_lo(u0), ay = sn * bf_hi(u0);
    int j = 0;
    for (; j + 8 <= nb; j += 8) {
        int2 m[8];
        unsigned u[8];
#pragma unroll
        for (int q = 0; q < 8; q++) m[q] = mbase[j + q];
#pragma unroll
        for (int q = 0; q < 8; q++) u[q] = HL[(size_t)m[q].x * 64 + lane];
#pragma unroll
        for (int q = 0; q < 8; q++) {
            float nv = __int_as_float(m[q].y);
            ax += nv * bf_lo(u[q]);
            ay += nv * bf_hi(u[q]);
        }
    }
    for (; j < nb; j++) {
        int2 m = mbase[j];
        unsigned u = HL[(size_t)m.x * 64 + lane];
        float nv = __int_as_float(m.y);
        ax += nv * bf_lo(u);
        ay += nv * bf_hi(u);
    }
    for (int e = e0 + 64; e < e1; e++) {           // rare high-degree tail
        int2 m = csr[e];
        unsigned u = HL[(size_t)m.x * 64 + lane];
        float nv = __int_as_float(m.y);
        ax += nv * bf_lo(u);
        ay += nv * bf_hi(u);
    }
    float2 bv = ((const float2*)bias)[lane];
    float rx = fmaxf(ax + bv.x, 0.f);
    float ry = fmaxf(ay + bv.y, 0.f);
    Hout[(size_t)node * 64 + lane] = pack_bf16x2(rx, ry);
}

// One block per graph: stream the sorted node segment, 4 waves stride it,
// LDS-combine, divide by count, write. No atomics.
__global__ __launch_bounds__(256) void k_pool(const unsigned* __restrict__ HB,
                                              const int* __restrict__ gb,
                                              float* __restrict__ outp) {
    __shared__ float part[4][128];
    int g = blockIdx.x;
    int lane = threadIdx.x & 63, w = threadIdx.x >> 6;
    int s = gb[g], e = gb[g + 1];
    float ax = 0.f, ay = 0.f;
    for (int i = s + w; i < e; i += 4) {
        unsigned u = HB[(size_t)i * 64 + lane];
        ax += bf_lo(u); ay += bf_hi(u);
    }
    part[w][lane * 2] = ax;
    part[w][lane * 2 + 1] = ay;
    __syncthreads();
    if (threadIdx.x < 128) {
        float sum = part[0][threadIdx.x] + part[1][threadIdx.x]
                  + part[2][threadIdx.x] + part[3][threadIdx.x];
        float c = (float)(e - s);
        outp[g * 128 + threadIdx.x] = sum / fmaxf(c, 1.0f);
    }
}

extern "C" void kernel_launch(void* const* d_in, const int* in_sizes, int n_in,
                              void* d_out, int out_size, void* d_ws, size_t ws_size,
                              hipStream_t stream) {
    const float* x     = (const float*)d_in[0];
    const int*   ei    = (const int*)d_in[1];
    const float* ew    = (const float*)d_in[2];
    const int*   batch = (const int*)d_in[3];
    const float* Wt[3] = {(const float*)d_in[4], (const float*)d_in[6], (const float*)d_in[8]};
    const float* bt[3] = {(const float*)d_in[5], (const float*)d_in[7], (const float*)d_in[9]};
    float* out = (float*)d_out;

    const int D = 128;
    const int N = in_sizes[0] / D;       // 100000
    const int E = in_sizes[2];           // 1600000
    const int G = out_size / (3 * D);    // 256

    // workspace carve-up (256 B aligned)
    char* p = (char*)d_ws;
    auto alloc = [&](size_t bytes) {
        void* r = (void*)p;
        p += (bytes + 255) & ~(size_t)255;
        return r;
    };
    float*    deg    = (float*)alloc((size_t)N * 4);       // becomes dinv
    int*      cnt    = (int*)alloc((size_t)N * 4);
    int*      cursor = (int*)alloc((size_t)N * 4);
    int*      ptr    = (int*)alloc((size_t)(N + 1) * 4);
    int*      pre    = (int*)alloc((size_t)N * 4);
    int*      bsum   = (int*)alloc((size_t)128 * 4);
    int*      gb     = (int*)alloc((size_t)(G + 1) * 4);
    int2*     csr    = (int2*)alloc((size_t)E * 8);
    unsigned* bufHL  = (unsigned*)alloc((size_t)N * 64 * 4);  // hl, bf16-packed
    unsigned* bufH   = (unsigned*)alloc((size_t)N * 64 * 4);  // h,  bf16-packed

    int nb = (N + 1023) / 1024;

    k_init<<<(N + 255) / 256, 256, 0, stream>>>(deg, cnt, N);
    k_deg_cnt<<<(E + 255) / 256, 256, 0, stream>>>(ei, ew, deg, cnt, E);
    k_dinv<<<(N + 255) / 256, 256, 0, stream>>>(deg, N);
    k_bounds<<<1, 512, 0, stream>>>(batch, gb, N, G);
    k_scan1<<<nb, 1024, 0, stream>>>(cnt, pre, bsum, N);
    k_scan2<<<1, 128, 0, stream>>>(bsum, nb, ptr, N);
    k_scan3<<<nb, 1024, 0, stream>>>(pre, bsum, ptr, cursor, N);
    k_fill<<<(E + 255) / 256, 256, 0, stream>>>(ei, ew, deg, cursor, csr, E);

    for (int l = 0; l < 3; l++) {
        if (l == 0)
            k_gemm<false><<<(N + 63) / 64, 256, 0, stream>>>(x, Wt[l], bufHL, N);
        else
            k_gemm<true><<<(N + 63) / 64, 256, 0, stream>>>(bufH, Wt[l], bufHL, N);
        k_agg<<<(N + 3) / 4, 256, 0, stream>>>(bufHL, ptr, csr, deg, bt[l], bufH, N);
        k_pool<<<G, 256, 0, stream>>>(bufH, gb, out + (size_t)l * G * D);
    }
}

// Round 5
// 675.705 us; speedup vs baseline: 2.0951x; 1.1320x over previous
//
#include <hip/hip_runtime.h>

// ---------------------------------------------------------------------------
// GCN block: 3 x (GCNConv -> ReLU -> global_mean_pool)
// Setup (ONE atomic stream total):
//   k_phase1: epos[e]=atomicAdd(cnt[col],1)        (only atomics, 1.6M)
//   scan cnt -> ptr
//   k_scatter: csr[ptr[c]+epos[e]]=(row, ew)       (plain stores, L2-absorbed)
//   k_degdinv: dinv[i]=rsqrt(1+sum bucket w)       (no atomics)
//   k_norm:    csr.w = dinv[r]*w*dinv[c]           (L2-resident dinv gathers)
//   k_bounds:  graph segment boundaries by binary search on sorted batch
// Per layer: GEMM (fp32 compute, bf16 in/out) -> gather-aggregate fp32
//   (LDS edge metadata, unroll-8) -> h bf16 -> segment pool (no atomics).
// ---------------------------------------------------------------------------

__device__ inline unsigned pack_bf16x2(float a, float b) {
    unsigned ua = __float_as_uint(a);
    ua = (ua + 0x7FFFu + ((ua >> 16) & 1u)) >> 16;       // RNE
    unsigned ub = __float_as_uint(b);
    ub = (ub + 0x7FFFu + ((ub >> 16) & 1u)) >> 16;
    return ua | (ub << 16);
}
__device__ inline float bf_lo(unsigned u) { return __uint_as_float(u << 16); }
__device__ inline float bf_hi(unsigned u) { return __uint_as_float(u & 0xFFFF0000u); }

__global__ void k_zero(int* __restrict__ cnt, int N) {
    int i = blockIdx.x * blockDim.x + threadIdx.x;
    if (i < N) cnt[i] = 0;
}

// The ONLY atomic kernel: per-edge rank within its destination bucket.
__global__ void k_phase1(const int* __restrict__ ei, int* __restrict__ cnt,
                         int* __restrict__ epos, int E) {
    int e = blockIdx.x * blockDim.x + threadIdx.x;
    if (e >= E) return;
    int c = ei[E + e];
    epos[e] = atomicAdd(&cnt[c], 1);
}

// --- multi-block exclusive scan: scan1 (per-block) -> scan2 (block sums) ---
__global__ __launch_bounds__(1024) void k_scan1(const int* __restrict__ cnt,
                                                int* __restrict__ pre,
                                                int* __restrict__ bsum, int n) {
    __shared__ int wsum[16];
    int t = threadIdx.x, lane = t & 63, w = t >> 6;
    int i = blockIdx.x * 1024 + t;
    int v = (i < n) ? cnt[i] : 0;
    int x = v;
#pragma unroll
    for (int off = 1; off < 64; off <<= 1) {
        int y = __shfl_up(x, off, 64);
        if (lane >= off) x += y;
    }
    if (lane == 63) wsum[w] = x;
    __syncthreads();
    int woff = 0, tot = 0;
#pragma unroll
    for (int q = 0; q < 16; q++) { int s = wsum[q]; if (q < w) woff += s; tot += s; }
    if (i < n) pre[i] = woff + x - v;
    if (t == 0) bsum[blockIdx.x] = tot;
}

__global__ __launch_bounds__(128) void k_scan2(int* __restrict__ bsum, int nb,
                                               int* __restrict__ ptrv, int n) {
    __shared__ int ws[2];
    int t = threadIdx.x, lane = t & 63, w = t >> 6;
    int v = (t < nb) ? bsum[t] : 0;
    int x = v;
#pragma unroll
    for (int off = 1; off < 64; off <<= 1) {
        int y = __shfl_up(x, off, 64);
        if (lane >= off) x += y;
    }
    if (lane == 63) ws[w] = x;
    __syncthreads();
    int woff = (w == 1) ? ws[0] : 0;
    int tot = ws[0] + ws[1];
    if (t < nb) bsum[t] = woff + x - v;
    if (t == 0) ptrv[n] = tot;
}

__global__ __launch_bounds__(1024) void k_scan3(const int* __restrict__ pre,
                                                const int* __restrict__ bsum,
                                                int* __restrict__ ptrv, int n) {
    int i = blockIdx.x * 1024 + threadIdx.x;
    if (i >= n) return;
    ptrv[i] = pre[i] + bsum[blockIdx.x];
}

// Scatter edges to CSR slots (plain stores; L2 write-back absorbs them).
__global__ void k_scatter(const int* __restrict__ ei, const float* __restrict__ ew,
                          const int* __restrict__ ptrv, const int* __restrict__ epos,
                          int2* __restrict__ csr, int E) {
    int e = blockIdx.x * blockDim.x + threadIdx.x;
    if (e >= E) return;
    int r = ei[e];
    int c = ei[E + e];
    int2 v; v.x = r; v.y = __float_as_int(ew[e]);
    csr[ptrv[c] + epos[e]] = v;
}

// deg = 1 (self-loop) + sum of bucket weights; dinv = rsqrt(deg). No atomics.
__global__ void k_degdinv(const int2* __restrict__ csr, const int* __restrict__ ptrv,
                          float* __restrict__ dinv, int N) {
    int i = blockIdx.x * blockDim.x + threadIdx.x;
    if (i >= N) return;
    float s = 1.0f;
    int e1 = ptrv[i + 1];
    for (int j = ptrv[i]; j < e1; j++) s += __int_as_float(csr[j].y);
    dinv[i] = (s > 0.f) ? rsqrtf(s) : 0.f;
}

// Rewrite bucket values to the symmetric-normalized edge coefficient.
__global__ void k_norm(int2* __restrict__ csr, const int* __restrict__ ptrv,
                       const float* __restrict__ dinv, int N) {
    int i = blockIdx.x * blockDim.x + threadIdx.x;
    if (i >= N) return;
    float dc = dinv[i];
    int e1 = ptrv[i + 1];
    for (int j = ptrv[i]; j < e1; j++) {
        int2 m = csr[j];
        m.y = __float_as_int(dinv[m.x] * __int_as_float(m.y) * dc);
        csr[j] = m;
    }
}

// gb[g] = lower_bound(batch, g) for g in [0, G]; counts[g] = gb[g+1]-gb[g].
__global__ void k_bounds(const int* __restrict__ batch, int* __restrict__ gb,
                         int N, int G) {
    int t = blockIdx.x * blockDim.x + threadIdx.x;
    if (t > G) return;
    int lo = 0, hi = N;
    while (lo < hi) { int mid = (lo + hi) >> 1; if (batch[mid] < t) lo = mid + 1; else hi = mid; }
    gb[t] = lo;
}

// hl = H @ W  (M x 128) @ (128 x 128), fp32 vector ALU, bf16-packed output.
// BF16IN: input rows are packed bf16 (N x 64 uint); else fp32 (N x 128).
template <bool BF16IN>
__global__ __launch_bounds__(256) void k_gemm(const void* __restrict__ Hin,
                                              const float* __restrict__ W,
                                              unsigned* __restrict__ O, int M) {
    __shared__ float sH[64 * 128];
    int t = threadIdx.x;
    int rbase = blockIdx.x * 64;
    int nrows = M - rbase; if (nrows > 64) nrows = 64;
    float4* sH4 = (float4*)sH;
    int nf = nrows * 32;                // 32 16B-groups per row either way
    if (BF16IN) {
        const uint2* H2 = (const uint2*)Hin + (size_t)rbase * 32;
#pragma unroll
        for (int i = 0; i < 8; i++) {
            int idx = t + i * 256;
            float4 f = make_float4(0.f, 0.f, 0.f, 0.f);
            if (idx < nf) {
                uint2 v = H2[idx];
                f.x = bf_lo(v.x); f.y = bf_hi(v.x);
                f.z = bf_lo(v.y); f.w = bf_hi(v.y);
            }
            sH4[idx] = f;
        }
    } else {
        const float4* H4 = (const float4*)Hin + (size_t)rbase * 32;
#pragma unroll
        for (int i = 0; i < 8; i++) {
            int idx = t + i * 256;
            float4 v = make_float4(0.f, 0.f, 0.f, 0.f);
            if (idx < nf) v = H4[idx];
            sH4[idx] = v;
        }
    }
    __syncthreads();
    int jc = t & 31;        // column group: cols 4*jc .. 4*jc+3
    int rg = t >> 5;        // row group:    rows 8*rg .. 8*rg+7
    const float4* W4 = (const float4*)W;
    float4 acc[8];
#pragma unroll
    for (int r = 0; r < 8; r++) acc[r] = make_float4(0.f, 0.f, 0.f, 0.f);
    const float* hrow = &sH[rg * 8 * 128];
#pragma unroll 4
    for (int k = 0; k < 128; k++) {
        float4 wv = W4[k * 32 + jc];
#pragma unroll
        for (int r = 0; r < 8; r++) {
            float hv = hrow[r * 128 + k];   // LDS broadcast
            acc[r].x += hv * wv.x;
            acc[r].y += hv * wv.y;
            acc[r].z += hv * wv.z;
            acc[r].w += hv * wv.w;
        }
    }
    uint2* O2 = (uint2*)O;
#pragma unroll
    for (int r = 0; r < 8; r++) {
        int row = rbase + rg * 8 + r;
        if (row < M) {
            uint2 pv;
            pv.x = pack_bf16x2(acc[r].x, acc[r].y);
            pv.y = pack_bf16x2(acc[r].z, acc[r].w);
            O2[(size_t)row * 32 + jc] = pv;
        }
    }
}

// One wave per node; hl rows 256 B (64 lanes x packed bf16x2). Edge metadata
// staged in LDS; unroll-8 gathers in flight. h written packed bf16.
__global__ __launch_bounds__(256) void k_agg(const unsigned* __restrict__ HL,
                                             const int* __restrict__ ptr,
                                             const int2* __restrict__ csr,
                                             const float* __restrict__ dinv,
                                             const float* __restrict__ bias,
                                             unsigned* __restrict__ Hout, int M) {
    __shared__ int2 sM[4 * 64];
    int node = (int)((blockIdx.x * blockDim.x + threadIdx.x) >> 6);
    if (node >= M) return;
    int lane = threadIdx.x & 63;
    int2* mbase = &sM[(threadIdx.x >> 6) * 64];
    int e0 = ptr[node], e1 = ptr[node + 1];
    int deg = e1 - e0;
    int nb = deg < 64 ? deg : 64;
    if (lane < nb) mbase[lane] = csr[e0 + lane];   // one coalesced load
    float di = dinv[node];
    float sn = di * di;                            // self-loop norm
    unsigned u0 = HL[(size_t)node * 64 + lane];
    float ax = sn * bf_lo(u0), ay = sn * bf_hi(u0);
    int j = 0;
    for (; j + 8 <= nb; j += 8) {
        int2 m[8];
        unsigned u[8];
#pragma unroll
        for (int q = 0; q < 8; q++) m[q] = mbase[j + q];
#pragma unroll
        for (int q = 0; q < 8; q++) u[q] = HL[(size_t)m[q].x * 64 + lane];
#pragma unroll
        for (int q = 0; q < 8; q++) {
            float nv = __int_as_float(m[q].y);
            ax += nv * bf_lo(u[q]);
            ay += nv * bf_hi(u[q]);
        }
    }
    for (; j < nb; j++) {
        int2 m = mbase[j];
        unsigned u = HL[(size_t)m.x * 64 + lane];
        float nv = __int_as_float(m.y);
        ax += nv * bf_lo(u);
        ay += nv * bf_hi(u);
    }
    for (int e = e0 + 64; e < e1; e++) {           // rare high-degree tail
        int2 m = csr[e];
        unsigned u = HL[(size_t)m.x * 64 + lane];
        float nv = __int_as_float(m.y);
        ax += nv * bf_lo(u);
        ay += nv * bf_hi(u);
    }
    float2 bv = ((const float2*)bias)[lane];
    float rx = fmaxf(ax + bv.x, 0.f);
    float ry = fmaxf(ay + bv.y, 0.f);
    Hout[(size_t)node * 64 + lane] = pack_bf16x2(rx, ry);
}

// One block per graph: stream the sorted node segment, 4 waves stride it,
// LDS-combine, divide by count, write. No atomics.
__global__ __launch_bounds__(256) void k_pool(const unsigned* __restrict__ HB,
                                              const int* __restrict__ gb,
                                              float* __restrict__ outp) {
    __shared__ float part[4][128];
    int g = blockIdx.x;
    int lane = threadIdx.x & 63, w = threadIdx.x >> 6;
    int s = gb[g], e = gb[g + 1];
    float ax = 0.f, ay = 0.f;
    for (int i = s + w; i < e; i += 4) {
        unsigned u = HB[(size_t)i * 64 + lane];
        ax += bf_lo(u); ay += bf_hi(u);
    }
    part[w][lane * 2] = ax;
    part[w][lane * 2 + 1] = ay;
    __syncthreads();
    if (threadIdx.x < 128) {
        float sum = part[0][threadIdx.x] + part[1][threadIdx.x]
                  + part[2][threadIdx.x] + part[3][threadIdx.x];
        float c = (float)(e - s);
        outp[g * 128 + threadIdx.x] = sum / fmaxf(c, 1.0f);
    }
}

extern "C" void kernel_launch(void* const* d_in, const int* in_sizes, int n_in,
                              void* d_out, int out_size, void* d_ws, size_t ws_size,
                              hipStream_t stream) {
    const float* x     = (const float*)d_in[0];
    const int*   ei    = (const int*)d_in[1];
    const float* ew    = (const float*)d_in[2];
    const int*   batch = (const int*)d_in[3];
    const float* Wt[3] = {(const float*)d_in[4], (const float*)d_in[6], (const float*)d_in[8]};
    const float* bt[3] = {(const float*)d_in[5], (const float*)d_in[7], (const float*)d_in[9]};
    float* out = (float*)d_out;

    const int D = 128;
    const int N = in_sizes[0] / D;       // 100000
    const int E = in_sizes[2];           // 1600000
    const int G = out_size / (3 * D);    // 256

    // workspace carve-up (256 B aligned)
    char* p = (char*)d_ws;
    auto alloc = [&](size_t bytes) {
        void* r = (void*)p;
        p += (bytes + 255) & ~(size_t)255;
        return r;
    };
    int*      cnt    = (int*)alloc((size_t)N * 4);
    int*      ptr    = (int*)alloc((size_t)(N + 1) * 4);
    int*      pre    = (int*)alloc((size_t)N * 4);
    int*      bsum   = (int*)alloc((size_t)128 * 4);
    int*      gb     = (int*)alloc((size_t)(G + 1) * 4);
    float*    dinv   = (float*)alloc((size_t)N * 4);
    int2*     csr    = (int2*)alloc((size_t)E * 8);
    unsigned* bufHL  = (unsigned*)alloc((size_t)N * 64 * 4);  // hl, bf16-packed
    unsigned* bufH   = (unsigned*)alloc((size_t)N * 64 * 4);  // h,  bf16-packed
    int*      epos   = (int*)bufH;   // alias: epos dead before bufH first write

    int nb = (N + 1023) / 1024;

    k_zero<<<(N + 255) / 256, 256, 0, stream>>>(cnt, N);
    k_phase1<<<(E + 255) / 256, 256, 0, stream>>>(ei, cnt, epos, E);
    k_bounds<<<1, 512, 0, stream>>>(batch, gb, N, G);
    k_scan1<<<nb, 1024, 0, stream>>>(cnt, pre, bsum, N);
    k_scan2<<<1, 128, 0, stream>>>(bsum, nb, ptr, N);
    k_scan3<<<nb, 1024, 0, stream>>>(pre, bsum, ptr, N);
    k_scatter<<<(E + 255) / 256, 256, 0, stream>>>(ei, ew, ptr, epos, csr, E);
    k_degdinv<<<(N + 255) / 256, 256, 0, stream>>>(csr, ptr, dinv, N);
    k_norm<<<(N + 255) / 256, 256, 0, stream>>>(csr, ptr, dinv, N);

    for (int l = 0; l < 3; l++) {
        if (l == 0)
            k_gemm<false><<<(N + 63) / 64, 256, 0, stream>>>(x, Wt[l], bufHL, N);
        else
            k_gemm<true><<<(N + 63) / 64, 256, 0, stream>>>(bufH, Wt[l], bufHL, N);
        k_agg<<<(N + 3) / 4, 256, 0, stream>>>(bufHL, ptr, csr, dinv, bt[l], bufH, N);
        k_pool<<<G, 256, 0, stream>>>(bufH, gb, out + (size_t)l * G * D);
    }
}

// Round 6
// 616.712 us; speedup vs baseline: 2.2955x; 1.0957x over previous
//
#include <hip/hip_runtime.h>

// ---------------------------------------------------------------------------
// GCN block: 3 x (GCNConv -> ReLU -> global_mean_pool)
// Setup (ONE atomic stream total):
//   k_phase1: epos[e]=atomicAdd(cnt[col],1)        (only atomics, 1.6M)
//   scan cnt -> ptr
//   k_scatter: csr[ptr[c]+epos[e]]=(row, ew)       (plain stores, L2-absorbed)
//   k_degdinv: dinv[i]=rsqrt(1+sum bucket w)       (no atomics)
//   k_norm:    csr.w = dinv[r]*w*dinv[c]           (L2-resident dinv gathers)
//   k_bounds:  graph segment boundaries by binary search on sorted batch
// Per layer:
//   L1: fp32 vector GEMM (fp32 x input) -> bf16 hl
//   L2/L3: MFMA bf16 GEMM (inputs already bf16 -> identical operands, fp32 acc)
//   -> gather-aggregate fp32 (LDS edge metadata, unroll-8) -> h bf16
//   -> segment pool per graph (no atomics).
// ---------------------------------------------------------------------------

typedef short short8 __attribute__((ext_vector_type(8)));   // 8 bf16 (4 VGPR)
typedef float f32x4  __attribute__((ext_vector_type(4)));   // MFMA C/D

__device__ inline unsigned pack_bf16x2(float a, float b) {
    unsigned ua = __float_as_uint(a);
    ua = (ua + 0x7FFFu + ((ua >> 16) & 1u)) >> 16;       // RNE
    unsigned ub = __float_as_uint(b);
    ub = (ub + 0x7FFFu + ((ub >> 16) & 1u)) >> 16;
    return ua | (ub << 16);
}
__device__ inline ushort bf16_1(float a) {
    unsigned ua = __float_as_uint(a);
    return (ushort)((ua + 0x7FFFu + ((ua >> 16) & 1u)) >> 16);
}
__device__ inline float bf_lo(unsigned u) { return __uint_as_float(u << 16); }
__device__ inline float bf_hi(unsigned u) { return __uint_as_float(u & 0xFFFF0000u); }

__global__ void k_zero(int* __restrict__ cnt, int N) {
    int i = blockIdx.x * blockDim.x + threadIdx.x;
    if (i < N) cnt[i] = 0;
}

// The ONLY atomic kernel: per-edge rank within its destination bucket.
__global__ void k_phase1(const int* __restrict__ ei, int* __restrict__ cnt,
                         int* __restrict__ epos, int E) {
    int e = blockIdx.x * blockDim.x + threadIdx.x;
    if (e >= E) return;
    int c = ei[E + e];
    epos[e] = atomicAdd(&cnt[c], 1);
}

// --- multi-block exclusive scan: scan1 (per-block) -> scan2 (block sums) ---
__global__ __launch_bounds__(1024) void k_scan1(const int* __restrict__ cnt,
                                                int* __restrict__ pre,
                                                int* __restrict__ bsum, int n) {
    __shared__ int wsum[16];
    int t = threadIdx.x, lane = t & 63, w = t >> 6;
    int i = blockIdx.x * 1024 + t;
    int v = (i < n) ? cnt[i] : 0;
    int x = v;
#pragma unroll
    for (int off = 1; off < 64; off <<= 1) {
        int y = __shfl_up(x, off, 64);
        if (lane >= off) x += y;
    }
    if (lane == 63) wsum[w] = x;
    __syncthreads();
    int woff = 0, tot = 0;
#pragma unroll
    for (int q = 0; q < 16; q++) { int s = wsum[q]; if (q < w) woff += s; tot += s; }
    if (i < n) pre[i] = woff + x - v;
    if (t == 0) bsum[blockIdx.x] = tot;
}

__global__ __launch_bounds__(128) void k_scan2(int* __restrict__ bsum, int nb,
                                               int* __restrict__ ptrv, int n) {
    __shared__ int ws[2];
    int t = threadIdx.x, lane = t & 63, w = t >> 6;
    int v = (t < nb) ? bsum[t] : 0;
    int x = v;
#pragma unroll
    for (int off = 1; off < 64; off <<= 1) {
        int y = __shfl_up(x, off, 64);
        if (lane >= off) x += y;
    }
    if (lane == 63) ws[w] = x;
    __syncthreads();
    int woff = (w == 1) ? ws[0] : 0;
    int tot = ws[0] + ws[1];
    if (t < nb) bsum[t] = woff + x - v;
    if (t == 0) ptrv[n] = tot;
}

__global__ __launch_bounds__(1024) void k_scan3(const int* __restrict__ pre,
                                                const int* __restrict__ bsum,
                                                int* __restrict__ ptrv, int n) {
    int i = blockIdx.x * 1024 + threadIdx.x;
    if (i >= n) return;
    ptrv[i] = pre[i] + bsum[blockIdx.x];
}

// Scatter edges to CSR slots (plain stores; L2 write-back absorbs them).
__global__ void k_scatter(const int* __restrict__ ei, const float* __restrict__ ew,
                          const int* __restrict__ ptrv, const int* __restrict__ epos,
                          int2* __restrict__ csr, int E) {
    int e = blockIdx.x * blockDim.x + threadIdx.x;
    if (e >= E) return;
    int r = ei[e];
    int c = ei[E + e];
    int2 v; v.x = r; v.y = __float_as_int(ew[e]);
    csr[ptrv[c] + epos[e]] = v;
}

// deg = 1 (self-loop) + sum of bucket weights; dinv = rsqrt(deg). No atomics.
__global__ void k_degdinv(const int2* __restrict__ csr, const int* __restrict__ ptrv,
                          float* __restrict__ dinv, int N) {
    int i = blockIdx.x * blockDim.x + threadIdx.x;
    if (i >= N) return;
    float s = 1.0f;
    int e1 = ptrv[i + 1];
    for (int j = ptrv[i]; j < e1; j++) s += __int_as_float(csr[j].y);
    dinv[i] = (s > 0.f) ? rsqrtf(s) : 0.f;
}

// Rewrite bucket values to the symmetric-normalized edge coefficient.
__global__ void k_norm(int2* __restrict__ csr, const int* __restrict__ ptrv,
                       const float* __restrict__ dinv, int N) {
    int i = blockIdx.x * blockDim.x + threadIdx.x;
    if (i >= N) return;
    float dc = dinv[i];
    int e1 = ptrv[i + 1];
    for (int j = ptrv[i]; j < e1; j++) {
        int2 m = csr[j];
        m.y = __float_as_int(dinv[m.x] * __int_as_float(m.y) * dc);
        csr[j] = m;
    }
}

// gb[g] = lower_bound(batch, g) for g in [0, G]; counts[g] = gb[g+1]-gb[g].
__global__ void k_bounds(const int* __restrict__ batch, int* __restrict__ gb,
                         int N, int G) {
    int t = blockIdx.x * blockDim.x + threadIdx.x;
    if (t > G) return;
    int lo = 0, hi = N;
    while (lo < hi) { int mid = (lo + hi) >> 1; if (batch[mid] < t) lo = mid + 1; else hi = mid; }
    gb[t] = lo;
}

// WbT[l][n][k] = bf16(W_l[k][n]) — B-operand prep (32 KB per layer, L1-hot).
__global__ void k_wprep(const float* __restrict__ W0, const float* __restrict__ W1,
                        const float* __restrict__ W2, ushort* __restrict__ WbT) {
    int l = blockIdx.y;
    const float* W = (l == 0) ? W0 : ((l == 1) ? W1 : W2);
    int id = blockIdx.x * 256 + threadIdx.x;   // 0..16383
    int n = id & 127, k = id >> 7;
    WbT[l * 16384 + n * 128 + k] = bf16_1(W[k * 128 + n]);
}

// Layer 1: hl = X @ W, fp32 vector ALU (fp32 input), bf16-packed output.
__global__ __launch_bounds__(256) void k_gemm_f32(const float* __restrict__ Hin,
                                                  const float* __restrict__ W,
                                                  unsigned* __restrict__ O, int M) {
    __shared__ float sH[64 * 128];
    int t = threadIdx.x;
    int rbase = blockIdx.x * 64;
    int nrows = M - rbase; if (nrows > 64) nrows = 64;
    float4* sH4 = (float4*)sH;
    int nf = nrows * 32;
    const float4* H4 = (const float4*)Hin + (size_t)rbase * 32;
#pragma unroll
    for (int i = 0; i < 8; i++) {
        int idx = t + i * 256;
        float4 v = make_float4(0.f, 0.f, 0.f, 0.f);
        if (idx < nf) v = H4[idx];
        sH4[idx] = v;
    }
    __syncthreads();
    int jc = t & 31;
    int rg = t >> 5;
    const float4* W4 = (const float4*)W;
    float4 acc[8];
#pragma unroll
    for (int r = 0; r < 8; r++) acc[r] = make_float4(0.f, 0.f, 0.f, 0.f);
    const float* hrow = &sH[rg * 8 * 128];
#pragma unroll 4
    for (int k = 0; k < 128; k++) {
        float4 wv = W4[k * 32 + jc];
#pragma unroll
        for (int r = 0; r < 8; r++) {
            float hv = hrow[r * 128 + k];
            acc[r].x += hv * wv.x;
            acc[r].y += hv * wv.y;
            acc[r].z += hv * wv.z;
            acc[r].w += hv * wv.w;
        }
    }
    uint2* O2 = (uint2*)O;
#pragma unroll
    for (int r = 0; r < 8; r++) {
        int row = rbase + rg * 8 + r;
        if (row < M) {
            uint2 pv;
            pv.x = pack_bf16x2(acc[r].x, acc[r].y);
            pv.y = pack_bf16x2(acc[r].z, acc[r].w);
            O2[(size_t)row * 32 + jc] = pv;
        }
    }
}

// Layers 2/3: hl = H @ W via v_mfma_f32_16x16x32_bf16.
// H is bf16-packed row-major (M x 64 u32). Wave = 32 rows x 128 cols:
// 2 m-strips x 8 n-tiles, 64 MFMAs. A-frag: A[m=lane&15][k=quad*8+j] ->
// 16 B/lane contiguous from H. B-frag: B[k=quad*8+j][n=lane&15] ->
// 16 B/lane contiguous from WbT[n][k]. Epilogue via LDS to row-major stores.
__global__ __launch_bounds__(256) void k_gemm_mfma(const unsigned* __restrict__ Hb,
                                                   const ushort* __restrict__ WbT,
                                                   unsigned* __restrict__ O, int M) {
    __shared__ unsigned sOut[4 * 32 * 64];     // 32 KB: 4 waves x 32 rows x 128 bf16
    int lane = threadIdx.x & 63;
    int wv = threadIdx.x >> 6;
    int quad = lane >> 4;
    int mrow = lane & 15;
    int m0 = blockIdx.x * 128 + wv * 32;
    int r0 = m0 + mrow;
    int r1 = r0 + 16;
    int r0c = r0 < M ? r0 : M - 1;             // clamp loads, guard stores
    int r1c = r1 < M ? r1 : M - 1;

    short8 a0[4], a1[4];
#pragma unroll
    for (int s = 0; s < 4; s++) {              // k-step s covers k in [32s,32s+32)
        a0[s] = *(const short8*)(Hb + (size_t)r0c * 64 + s * 16 + quad * 4);
        a1[s] = *(const short8*)(Hb + (size_t)r1c * 64 + s * 16 + quad * 4);
    }
    f32x4 acc0[8], acc1[8];
#pragma unroll
    for (int t = 0; t < 8; t++) {
        acc0[t] = (f32x4){0.f, 0.f, 0.f, 0.f};
        acc1[t] = (f32x4){0.f, 0.f, 0.f, 0.f};
    }
#pragma unroll
    for (int s = 0; s < 4; s++) {
#pragma unroll
        for (int t = 0; t < 8; t++) {
            short8 b = *(const short8*)(WbT + (t * 16 + mrow) * 128 + s * 32 + quad * 8);
            acc0[t] = __builtin_amdgcn_mfma_f32_16x16x32_bf16(a0[s], b, acc0[t], 0, 0, 0);
            acc1[t] = __builtin_amdgcn_mfma_f32_16x16x32_bf16(a1[s], b, acc1[t], 0, 0, 0);
        }
    }
    // C/D layout: col = lane&15, row = quad*4 + reg. Write bf16 to LDS, read
    // back row-major for coalesced u32 global stores.
    ushort* so = (ushort*)(sOut + wv * 32 * 64);
#pragma unroll
    for (int t = 0; t < 8; t++) {
#pragma unroll
        for (int r = 0; r < 4; r++) {
            int lr = quad * 4 + r;
            int c = t * 16 + mrow;
            so[lr * 128 + c] = bf16_1(acc0[t][r]);
            so[(lr + 16) * 128 + c] = bf16_1(acc1[t][r]);
        }
    }
    __syncthreads();
    const unsigned* si = sOut + wv * 32 * 64;
#pragma unroll 8
    for (int r = 0; r < 32; r++) {
        int row = m0 + r;
        if (row < M) O[(size_t)row * 64 + lane] = si[r * 64 + lane];
    }
}

// One wave per node; hl rows 256 B (64 lanes x packed bf16x2). Edge metadata
// staged in LDS; unroll-8 gathers in flight. h written packed bf16.
__global__ __launch_bounds__(256) void k_agg(const unsigned* __restrict__ HL,
                                             const int* __restrict__ ptr,
                                             const int2* __restrict__ csr,
                                             const float* __restrict__ dinv,
                                             const float* __restrict__ bias,
                                             unsigned* __restrict__ Hout, int M) {
    __shared__ int2 sM[4 * 64];
    int node = (int)((blockIdx.x * blockDim.x + threadIdx.x) >> 6);
    if (node >= M) return;
    int lane = threadIdx.x & 63;
    int2* mbase = &sM[(threadIdx.x >> 6) * 64];
    int e0 = ptr[node], e1 = ptr[node + 1];
    int deg = e1 - e0;
    int nb = deg < 64 ? deg : 64;
    if (lane < nb) mbase[lane] = csr[e0 + lane];   // one coalesced load
    float di = dinv[node];
    float sn = di * di;                            // self-loop norm
    unsigned u0 = HL[(size_t)node * 64 + lane];
    float ax = sn * bf_lo(u0), ay = sn * bf_hi(u0);
    int j = 0;
    for (; j + 8 <= nb; j += 8) {
        int2 m[8];
        unsigned u[8];
#pragma unroll
        for (int q = 0; q < 8; q++) m[q] = mbase[j + q];
#pragma unroll
        for (int q = 0; q < 8; q++) u[q] = HL[(size_t)m[q].x * 64 + lane];
#pragma unroll
        for (int q = 0; q < 8; q++) {
            float nv = __int_as_float(m[q].y);
            ax += nv * bf_lo(u[q]);
            ay += nv * bf_hi(u[q]);
        }
    }
    for (; j < nb; j++) {
        int2 m = mbase[j];
        unsigned u = HL[(size_t)m.x * 64 + lane];
        float nv = __int_as_float(m.y);
        ax += nv * bf_lo(u);
        ay += nv * bf_hi(u);
    }
    for (int e = e0 + 64; e < e1; e++) {           // rare high-degree tail
        int2 m = csr[e];
        unsigned u = HL[(size_t)m.x * 64 + lane];
        float nv = __int_as_float(m.y);
        ax += nv * bf_lo(u);
        ay += nv * bf_hi(u);
    }
    float2 bv = ((const float2*)bias)[lane];
    float rx = fmaxf(ax + bv.x, 0.f);
    float ry = fmaxf(ay + bv.y, 0.f);
    Hout[(size_t)node * 64 + lane] = pack_bf16x2(rx, ry);
}

// One block per graph: stream the sorted node segment, 4 waves stride it,
// LDS-combine, divide by count, write. No atomics.
__global__ __launch_bounds__(256) void k_pool(const unsigned* __restrict__ HB,
                                              const int* __restrict__ gb,
                                              float* __restrict__ outp) {
    __shared__ float part[4][128];
    int g = blockIdx.x;
    int lane = threadIdx.x & 63, w = threadIdx.x >> 6;
    int s = gb[g], e = gb[g + 1];
    float ax = 0.f, ay = 0.f;
    for (int i = s + w; i < e; i += 4) {
        unsigned u = HB[(size_t)i * 64 + lane];
        ax += bf_lo(u); ay += bf_hi(u);
    }
    part[w][lane * 2] = ax;
    part[w][lane * 2 + 1] = ay;
    __syncthreads();
    if (threadIdx.x < 128) {
        float sum = part[0][threadIdx.x] + part[1][threadIdx.x]
                  + part[2][threadIdx.x] + part[3][threadIdx.x];
        float c = (float)(e - s);
        outp[g * 128 + threadIdx.x] = sum / fmaxf(c, 1.0f);
    }
}

extern "C" void kernel_launch(void* const* d_in, const int* in_sizes, int n_in,
                              void* d_out, int out_size, void* d_ws, size_t ws_size,
                              hipStream_t stream) {
    const float* x     = (const float*)d_in[0];
    const int*   ei    = (const int*)d_in[1];
    const float* ew    = (const float*)d_in[2];
    const int*   batch = (const int*)d_in[3];
    const float* Wt[3] = {(const float*)d_in[4], (const float*)d_in[6], (const float*)d_in[8]};
    const float* bt[3] = {(const float*)d_in[5], (const float*)d_in[7], (const float*)d_in[9]};
    float* out = (float*)d_out;

    const int D = 128;
    const int N = in_sizes[0] / D;       // 100000
    const int E = in_sizes[2];           // 1600000
    const int G = out_size / (3 * D);    // 256

    // workspace carve-up (256 B aligned)
    char* p = (char*)d_ws;
    auto alloc = [&](size_t bytes) {
        void* r = (void*)p;
        p += (bytes + 255) & ~(size_t)255;
        return r;
    };
    int*      cnt    = (int*)alloc((size_t)N * 4);
    int*      ptr    = (int*)alloc((size_t)(N + 1) * 4);
    int*      pre    = (int*)alloc((size_t)N * 4);
    int*      bsum   = (int*)alloc((size_t)128 * 4);
    int*      gb     = (int*)alloc((size_t)(G + 1) * 4);
    float*    dinv   = (float*)alloc((size_t)N * 4);
    ushort*   WbT    = (ushort*)alloc((size_t)3 * 16384 * 2);
    int2*     csr    = (int2*)alloc((size_t)E * 8);
    unsigned* bufHL  = (unsigned*)alloc((size_t)N * 64 * 4);  // hl, bf16-packed
    unsigned* bufH   = (unsigned*)alloc((size_t)N * 64 * 4);  // h,  bf16-packed
    int*      epos   = (int*)bufH;   // alias: epos dead before bufH first write

    int nb = (N + 1023) / 1024;

    k_zero<<<(N + 255) / 256, 256, 0, stream>>>(cnt, N);
    k_phase1<<<(E + 255) / 256, 256, 0, stream>>>(ei, cnt, epos, E);
    k_bounds<<<1, 512, 0, stream>>>(batch, gb, N, G);
    k_wprep<<<dim3(64, 3), 256, 0, stream>>>(Wt[0], Wt[1], Wt[2], WbT);
    k_scan1<<<nb, 1024, 0, stream>>>(cnt, pre, bsum, N);
    k_scan2<<<1, 128, 0, stream>>>(bsum, nb, ptr, N);
    k_scan3<<<nb, 1024, 0, stream>>>(pre, bsum, ptr, N);
    k_scatter<<<(E + 255) / 256, 256, 0, stream>>>(ei, ew, ptr, epos, csr, E);
    k_degdinv<<<(N + 255) / 256, 256, 0, stream>>>(csr, ptr, dinv, N);
    k_norm<<<(N + 255) / 256, 256, 0, stream>>>(csr, ptr, dinv, N);

    for (int l = 0; l < 3; l++) {
        if (l == 0)
            k_gemm_f32<<<(N + 63) / 64, 256, 0, stream>>>(x, Wt[0], bufHL, N);
        else
            k_gemm_mfma<<<(N + 127) / 128, 256, 0, stream>>>(bufH, WbT + (size_t)l * 16384,
                                                             bufHL, N);
        k_agg<<<(N + 3) / 4, 256, 0, stream>>>(bufHL, ptr, csr, dinv, bt[l], bufH, N);
        k_pool<<<G, 256, 0, stream>>>(bufH, gb, out + (size_t)l * G * D);
    }
}

// Round 7
// 600.730 us; speedup vs baseline: 2.3565x; 1.0266x over previous
//
#include <hip/hip_runtime.h>

// ---------------------------------------------------------------------------
// GCN block: 3 x (GCNConv -> ReLU -> global_mean_pool)
// Setup (ONE atomic stream total):
//   k_phase1: epos[e]=atomicAdd(cnt[col],1)        (only atomics, 1.6M)
//   scan cnt -> ptr
//   k_scatter: csr[ptr[c]+epos[e]]=(row, ew)       (plain stores, L2-absorbed)
//   k_degdinv: dinv[i]=rsqrt(1+sum bucket w)       (no atomics)
//   k_norm:    csr.w = dinv[r]*w*dinv[c]           (L2-resident dinv gathers)
//   k_bounds:  graph segment boundaries by binary search on sorted batch
// Per layer:
//   GEMM via v_mfma_f32_16x16x32_bf16 (L1 fuses fp32->bf16 A-cast in-kernel)
//   -> gather-aggregate fp32, paired-edge: half-wave per edge, uint2/lane
//      (one load inst = two 256B rows), cross-half shfl_xor reduce
//   -> h bf16 -> segment pool per graph (no atomics).
// ---------------------------------------------------------------------------

typedef short short8 __attribute__((ext_vector_type(8)));   // 8 bf16 (4 VGPR)
typedef float f32x4  __attribute__((ext_vector_type(4)));   // MFMA C/D

__device__ inline unsigned pack_bf16x2(float a, float b) {
    unsigned ua = __float_as_uint(a);
    ua = (ua + 0x7FFFu + ((ua >> 16) & 1u)) >> 16;       // RNE
    unsigned ub = __float_as_uint(b);
    ub = (ub + 0x7FFFu + ((ub >> 16) & 1u)) >> 16;
    return ua | (ub << 16);
}
__device__ inline ushort bf16_1(float a) {
    unsigned ua = __float_as_uint(a);
    return (ushort)((ua + 0x7FFFu + ((ua >> 16) & 1u)) >> 16);
}
__device__ inline float bf_lo(unsigned u) { return __uint_as_float(u << 16); }
__device__ inline float bf_hi(unsigned u) { return __uint_as_float(u & 0xFFFF0000u); }

__global__ void k_zero(int* __restrict__ cnt, int N) {
    int i = blockIdx.x * blockDim.x + threadIdx.x;
    if (i < N) cnt[i] = 0;
}

// The ONLY atomic kernel: per-edge rank within its destination bucket.
__global__ void k_phase1(const int* __restrict__ ei, int* __restrict__ cnt,
                         int* __restrict__ epos, int E) {
    int e = blockIdx.x * blockDim.x + threadIdx.x;
    if (e >= E) return;
    int c = ei[E + e];
    epos[e] = atomicAdd(&cnt[c], 1);
}

// --- multi-block exclusive scan: scan1 (per-block) -> scan2 (block sums) ---
__global__ __launch_bounds__(1024) void k_scan1(const int* __restrict__ cnt,
                                                int* __restrict__ pre,
                                                int* __restrict__ bsum, int n) {
    __shared__ int wsum[16];
    int t = threadIdx.x, lane = t & 63, w = t >> 6;
    int i = blockIdx.x * 1024 + t;
    int v = (i < n) ? cnt[i] : 0;
    int x = v;
#pragma unroll
    for (int off = 1; off < 64; off <<= 1) {
        int y = __shfl_up(x, off, 64);
        if (lane >= off) x += y;
    }
    if (lane == 63) wsum[w] = x;
    __syncthreads();
    int woff = 0, tot = 0;
#pragma unroll
    for (int q = 0; q < 16; q++) { int s = wsum[q]; if (q < w) woff += s; tot += s; }
    if (i < n) pre[i] = woff + x - v;
    if (t == 0) bsum[blockIdx.x] = tot;
}

__global__ __launch_bounds__(128) void k_scan2(int* __restrict__ bsum, int nb,
                                               int* __restrict__ ptrv, int n) {
    __shared__ int ws[2];
    int t = threadIdx.x, lane = t & 63, w = t >> 6;
    int v = (t < nb) ? bsum[t] : 0;
    int x = v;
#pragma unroll
    for (int off = 1; off < 64; off <<= 1) {
        int y = __shfl_up(x, off, 64);
        if (lane >= off) x += y;
    }
    if (lane == 63) ws[w] = x;
    __syncthreads();
    int woff = (w == 1) ? ws[0] : 0;
    int tot = ws[0] + ws[1];
    if (t < nb) bsum[t] = woff + x - v;
    if (t == 0) ptrv[n] = tot;
}

__global__ __launch_bounds__(1024) void k_scan3(const int* __restrict__ pre,
                                                const int* __restrict__ bsum,
                                                int* __restrict__ ptrv, int n) {
    int i = blockIdx.x * 1024 + threadIdx.x;
    if (i >= n) return;
    ptrv[i] = pre[i] + bsum[blockIdx.x];
}

// Scatter edges to CSR slots (plain stores; L2 write-back absorbs them).
__global__ void k_scatter(const int* __restrict__ ei, const float* __restrict__ ew,
                          const int* __restrict__ ptrv, const int* __restrict__ epos,
                          int2* __restrict__ csr, int E) {
    int e = blockIdx.x * blockDim.x + threadIdx.x;
    if (e >= E) return;
    int r = ei[e];
    int c = ei[E + e];
    int2 v; v.x = r; v.y = __float_as_int(ew[e]);
    csr[ptrv[c] + epos[e]] = v;
}

// deg = 1 (self-loop) + sum of bucket weights; dinv = rsqrt(deg). No atomics.
__global__ void k_degdinv(const int2* __restrict__ csr, const int* __restrict__ ptrv,
                          float* __restrict__ dinv, int N) {
    int i = blockIdx.x * blockDim.x + threadIdx.x;
    if (i >= N) return;
    float s = 1.0f;
    int e1 = ptrv[i + 1];
    for (int j = ptrv[i]; j < e1; j++) s += __int_as_float(csr[j].y);
    dinv[i] = (s > 0.f) ? rsqrtf(s) : 0.f;
}

// Rewrite bucket values to the symmetric-normalized edge coefficient.
__global__ void k_norm(int2* __restrict__ csr, const int* __restrict__ ptrv,
                       const float* __restrict__ dinv, int N) {
    int i = blockIdx.x * blockDim.x + threadIdx.x;
    if (i >= N) return;
    float dc = dinv[i];
    int e1 = ptrv[i + 1];
    for (int j = ptrv[i]; j < e1; j++) {
        int2 m = csr[j];
        m.y = __float_as_int(dinv[m.x] * __int_as_float(m.y) * dc);
        csr[j] = m;
    }
}

// gb[g] = lower_bound(batch, g) for g in [0, G]; counts[g] = gb[g+1]-gb[g].
__global__ void k_bounds(const int* __restrict__ batch, int* __restrict__ gb,
                         int N, int G) {
    int t = blockIdx.x * blockDim.x + threadIdx.x;
    if (t > G) return;
    int lo = 0, hi = N;
    while (lo < hi) { int mid = (lo + hi) >> 1; if (batch[mid] < t) lo = mid + 1; else hi = mid; }
    gb[t] = lo;
}

// WbT[l][n][k] = bf16(W_l[k][n]) — B-operand prep (32 KB per layer, L1-hot).
__global__ void k_wprep(const float* __restrict__ W0, const float* __restrict__ W1,
                        const float* __restrict__ W2, ushort* __restrict__ WbT) {
    int l = blockIdx.y;
    const float* W = (l == 0) ? W0 : ((l == 1) ? W1 : W2);
    int id = blockIdx.x * 256 + threadIdx.x;   // 0..16383
    int n = id & 127, k = id >> 7;
    WbT[l * 16384 + n * 128 + k] = bf16_1(W[k * 128 + n]);
}

// hl = H @ W via v_mfma_f32_16x16x32_bf16. Wave = 32 rows x 128 cols:
// 2 m-strips x 8 n-tiles, 64 MFMAs. A-frag: A[m=lane&15][k=quad*8+j] ->
// 16 B/lane contiguous (F32IN: 32 B fp32 loaded and cast to bf16 in-kernel).
// B-frag: B[k=quad*8+j][n=lane&15] -> 16 B/lane contiguous from WbT[n][k].
// Epilogue via LDS to row-major coalesced u32 stores.
template <bool F32IN>
__global__ __launch_bounds__(256) void k_gemm_mfma(const void* __restrict__ Hin,
                                                   const ushort* __restrict__ WbT,
                                                   unsigned* __restrict__ O, int M) {
    __shared__ unsigned sOut[4 * 32 * 64];     // 32 KB: 4 waves x 32 rows x 128 bf16
    int lane = threadIdx.x & 63;
    int wv = threadIdx.x >> 6;
    int quad = lane >> 4;
    int mrow = lane & 15;
    int m0 = blockIdx.x * 128 + wv * 32;
    int r0 = m0 + mrow;
    int r1 = r0 + 16;
    int r0c = r0 < M ? r0 : M - 1;             // clamp loads, guard stores
    int r1c = r1 < M ? r1 : M - 1;

    short8 a0[4], a1[4];
    if (F32IN) {
        const float* Hf = (const float*)Hin;
#pragma unroll
        for (int s = 0; s < 4; s++) {          // k-step s covers k in [32s,32s+32)
            const float4* p0 = (const float4*)(Hf + (size_t)r0c * 128 + s * 32 + quad * 8);
            const float4* p1 = (const float4*)(Hf + (size_t)r1c * 128 + s * 32 + quad * 8);
            float4 f0 = p0[0], f1 = p0[1];
            float4 g0 = p1[0], g1 = p1[1];
            union { short8 s8; unsigned u[4]; } t0, t1;
            t0.u[0] = pack_bf16x2(f0.x, f0.y); t0.u[1] = pack_bf16x2(f0.z, f0.w);
            t0.u[2] = pack_bf16x2(f1.x, f1.y); t0.u[3] = pack_bf16x2(f1.z, f1.w);
            t1.u[0] = pack_bf16x2(g0.x, g0.y); t1.u[1] = pack_bf16x2(g0.z, g0.w);
            t1.u[2] = pack_bf16x2(g1.x, g1.y); t1.u[3] = pack_bf16x2(g1.z, g1.w);
            a0[s] = t0.s8; a1[s] = t1.s8;
        }
    } else {
        const unsigned* Hb = (const unsigned*)Hin;
#pragma unroll
        for (int s = 0; s < 4; s++) {
            a0[s] = *(const short8*)(Hb + (size_t)r0c * 64 + s * 16 + quad * 4);
            a1[s] = *(const short8*)(Hb + (size_t)r1c * 64 + s * 16 + quad * 4);
        }
    }
    f32x4 acc0[8], acc1[8];
#pragma unroll
    for (int t = 0; t < 8; t++) {
        acc0[t] = (f32x4){0.f, 0.f, 0.f, 0.f};
        acc1[t] = (f32x4){0.f, 0.f, 0.f, 0.f};
    }
#pragma unroll
    for (int s = 0; s < 4; s++) {
#pragma unroll
        for (int t = 0; t < 8; t++) {
            short8 b = *(const short8*)(WbT + (t * 16 + mrow) * 128 + s * 32 + quad * 8);
            acc0[t] = __builtin_amdgcn_mfma_f32_16x16x32_bf16(a0[s], b, acc0[t], 0, 0, 0);
            acc1[t] = __builtin_amdgcn_mfma_f32_16x16x32_bf16(a1[s], b, acc1[t], 0, 0, 0);
        }
    }
    // C/D layout: col = lane&15, row = quad*4 + reg. Write bf16 to LDS, read
    // back row-major for coalesced u32 global stores.
    ushort* so = (ushort*)(sOut + wv * 32 * 64);
#pragma unroll
    for (int t = 0; t < 8; t++) {
#pragma unroll
        for (int r = 0; r < 4; r++) {
            int lr = quad * 4 + r;
            int c = t * 16 + mrow;
            so[lr * 128 + c] = bf16_1(acc0[t][r]);
            so[(lr + 16) * 128 + c] = bf16_1(acc1[t][r]);
        }
    }
    __syncthreads();
    const unsigned* si = sOut + wv * 32 * 64;
#pragma unroll 8
    for (int r = 0; r < 32; r++) {
        int row = m0 + r;
        if (row < M) O[(size_t)row * 64 + lane] = si[r * 64 + lane];
    }
}

// One wave per node, paired-edge: lanes 0-31 take even edges, lanes 32-63 odd
// edges of the SAME node (no divergence). Each lane loads uint2 (4 features),
// so one load instruction fetches two 256B rows. Cross-half shfl_xor(32)
// merges the partials; half 0 stores.
__global__ __launch_bounds__(256) void k_agg(const unsigned* __restrict__ HL,
                                             const int* __restrict__ ptr,
                                             const int2* __restrict__ csr,
                                             const float* __restrict__ dinv,
                                             const float* __restrict__ bias,
                                             unsigned* __restrict__ Hout, int M) {
    __shared__ int2 sM[4 * 64];
    int node = (int)((blockIdx.x * blockDim.x + threadIdx.x) >> 6);
    if (node >= M) return;
    int lane = threadIdx.x & 63;
    int half = lane >> 5;                 // 0: even edges, 1: odd edges
    int q = lane & 31;                    // features 4q .. 4q+3
    int2* mbase = &sM[(threadIdx.x >> 6) * 64];
    int e0 = ptr[node], e1 = ptr[node + 1];
    int deg = e1 - e0;
    int nbv = deg < 64 ? deg : 64;
    if (lane < nbv) mbase[lane] = csr[e0 + lane];   // one coalesced load
    const uint2* HL2 = (const uint2*)HL;            // row = 32 uint2
    float di = dinv[node];
    float sn = (half == 0) ? di * di : 0.f;         // self-loop on half 0 only
    uint2 us = HL2[(size_t)node * 32 + q];          // both halves same lines
    float a0 = sn * bf_lo(us.x), a1 = sn * bf_hi(us.x);
    float a2 = sn * bf_lo(us.y), a3 = sn * bf_hi(us.y);
    int j = half;
    for (; j + 8 <= nbv; j += 8) {                  // 4 pairs in flight
        int2 m[4]; uint2 u[4];
#pragma unroll
        for (int t = 0; t < 4; t++) m[t] = mbase[j + 2 * t];
#pragma unroll
        for (int t = 0; t < 4; t++) u[t] = HL2[(size_t)m[t].x * 32 + q];
#pragma unroll
        for (int t = 0; t < 4; t++) {
            float nv = __int_as_float(m[t].y);
            a0 += nv * bf_lo(u[t].x); a1 += nv * bf_hi(u[t].x);
            a2 += nv * bf_lo(u[t].y); a3 += nv * bf_hi(u[t].y);
        }
    }
    for (; j < nbv; j += 2) {
        int2 m = mbase[j];
        uint2 u = HL2[(size_t)m.x * 32 + q];
        float nv = __int_as_float(m.y);
        a0 += nv * bf_lo(u.x); a1 += nv * bf_hi(u.x);
        a2 += nv * bf_lo(u.y); a3 += nv * bf_hi(u.y);
    }
    for (int e = e0 + 64 + half; e < e1; e += 2) {  // rare high-degree tail
        int2 m = csr[e];
        uint2 u = HL2[(size_t)m.x * 32 + q];
        float nv = __int_as_float(m.y);
        a0 += nv * bf_lo(u.x); a1 += nv * bf_hi(u.x);
        a2 += nv * bf_lo(u.y); a3 += nv * bf_hi(u.y);
    }
    a0 += __shfl_xor(a0, 32, 64);
    a1 += __shfl_xor(a1, 32, 64);
    a2 += __shfl_xor(a2, 32, 64);
    a3 += __shfl_xor(a3, 32, 64);
    float4 bv = ((const float4*)bias)[q];
    float r0 = fmaxf(a0 + bv.x, 0.f);
    float r1 = fmaxf(a1 + bv.y, 0.f);
    float r2 = fmaxf(a2 + bv.z, 0.f);
    float r3 = fmaxf(a3 + bv.w, 0.f);
    if (half == 0) {
        uint2 pv;
        pv.x = pack_bf16x2(r0, r1);
        pv.y = pack_bf16x2(r2, r3);
        ((uint2*)(Hout + (size_t)node * 64))[q] = pv;
    }
}

// One block per graph: stream the sorted node segment, 4 waves stride it,
// LDS-combine, divide by count, write. No atomics.
__global__ __launch_bounds__(256) void k_pool(const unsigned* __restrict__ HB,
                                              const int* __restrict__ gb,
                                              float* __restrict__ outp) {
    __shared__ float part[4][128];
    int g = blockIdx.x;
    int lane = threadIdx.x & 63, w = threadIdx.x >> 6;
    int s = gb[g], e = gb[g + 1];
    float ax = 0.f, ay = 0.f;
    for (int i = s + w; i < e; i += 4) {
        unsigned u = HB[(size_t)i * 64 + lane];
        ax += bf_lo(u); ay += bf_hi(u);
    }
    part[w][lane * 2] = ax;
    part[w][lane * 2 + 1] = ay;
    __syncthreads();
    if (threadIdx.x < 128) {
        float sum = part[0][threadIdx.x] + part[1][threadIdx.x]
                  + part[2][threadIdx.x] + part[3][threadIdx.x];
        float c = (float)(e - s);
        outp[g * 128 + threadIdx.x] = sum / fmaxf(c, 1.0f);
    }
}

extern "C" void kernel_launch(void* const* d_in, const int* in_sizes, int n_in,
                              void* d_out, int out_size, void* d_ws, size_t ws_size,
                              hipStream_t stream) {
    const float* x     = (const float*)d_in[0];
    const int*   ei    = (const int*)d_in[1];
    const float* ew    = (const float*)d_in[2];
    const int*   batch = (const int*)d_in[3];
    const float* Wt[3] = {(const float*)d_in[4], (const float*)d_in[6], (const float*)d_in[8]};
    const float* bt[3] = {(const float*)d_in[5], (const float*)d_in[7], (const float*)d_in[9]};
    float* out = (float*)d_out;

    const int D = 128;
    const int N = in_sizes[0] / D;       // 100000
    const int E = in_sizes[2];           // 1600000
    const int G = out_size / (3 * D);    // 256

    // workspace carve-up (256 B aligned)
    char* p = (char*)d_ws;
    auto alloc = [&](size_t bytes) {
        void* r = (void*)p;
        p += (bytes + 255) & ~(size_t)255;
        return r;
    };
    int*      cnt    = (int*)alloc((size_t)N * 4);
    int*      ptr    = (int*)alloc((size_t)(N + 1) * 4);
    int*      pre    = (int*)alloc((size_t)N * 4);
    int*      bsum   = (int*)alloc((size_t)128 * 4);
    int*      gb     = (int*)alloc((size_t)(G + 1) * 4);
    float*    dinv   = (float*)alloc((size_t)N * 4);
    ushort*   WbT    = (ushort*)alloc((size_t)3 * 16384 * 2);
    int2*     csr    = (int2*)alloc((size_t)E * 8);
    unsigned* bufHL  = (unsigned*)alloc((size_t)N * 64 * 4);  // hl, bf16-packed
    unsigned* bufH   = (unsigned*)alloc((size_t)N * 64 * 4);  // h,  bf16-packed
    int*      epos   = (int*)bufH;   // alias: epos dead before bufH first write

    int nb = (N + 1023) / 1024;

    k_zero<<<(N + 255) / 256, 256, 0, stream>>>(cnt, N);
    k_phase1<<<(E + 255) / 256, 256, 0, stream>>>(ei, cnt, epos, E);
    k_bounds<<<1, 512, 0, stream>>>(batch, gb, N, G);
    k_wprep<<<dim3(64, 3), 256, 0, stream>>>(Wt[0], Wt[1], Wt[2], WbT);
    k_scan1<<<nb, 1024, 0, stream>>>(cnt, pre, bsum, N);
    k_scan2<<<1, 128, 0, stream>>>(bsum, nb, ptr, N);
    k_scan3<<<nb, 1024, 0, stream>>>(pre, bsum, ptr, N);
    k_scatter<<<(E + 255) / 256, 256, 0, stream>>>(ei, ew, ptr, epos, csr, E);
    k_degdinv<<<(N + 255) / 256, 256, 0, stream>>>(csr, ptr, dinv, N);
    k_norm<<<(N + 255) / 256, 256, 0, stream>>>(csr, ptr, dinv, N);

    for (int l = 0; l < 3; l++) {
        if (l == 0)
            k_gemm_mfma<true><<<(N + 127) / 128, 256, 0, stream>>>(x, WbT, bufHL, N);
        else
            k_gemm_mfma<false><<<(N + 127) / 128, 256, 0, stream>>>(bufH, WbT + (size_t)l * 16384,
                                                                    bufHL, N);
        k_agg<<<(N + 3) / 4, 256, 0, stream>>>(bufHL, ptr, csr, dinv, bt[l], bufH, N);
        k_pool<<<G, 256, 0, stream>>>(bufH, gb, out + (size_t)l * G * D);
    }
}

// Round 8
// 596.954 us; speedup vs baseline: 2.3715x; 1.0063x over previous
//
#include <hip/hip_runtime.h>

// ---------------------------------------------------------------------------
// GCN block: 3 x (GCNConv -> ReLU -> global_mean_pool)
// Setup (ONE atomic stream total):
//   k_prep:   zero cnt + graph bounds (binary search) + WbT prep  (fused)
//   k_phase1: epos[e]=atomicAdd(cnt[col],1)  (only atomics, 1.6M)
//             + grid-stride fp32->bf16 cast of x (hidden under atomic latency)
//   scan cnt -> ptr
//   k_scatter: csr[ptr[c]+epos[e]]=(row, ew)       (plain stores, L2-absorbed)
//   k_degdinv: half-wave per node, coalesced bucket reads, shfl reduce
//   k_norm:    half-wave per node, coalesced int2 RMW, L2-hot dinv gathers
// Per layer:
//   GEMM via v_mfma_f32_16x16x32_bf16 (all bf16-packed inputs)
//   -> gather-aggregate fp32, paired-edge half-waves, uint2/lane
//   -> h bf16 -> segment pool per graph (no atomics).
// ---------------------------------------------------------------------------

typedef short short8 __attribute__((ext_vector_type(8)));   // 8 bf16 (4 VGPR)
typedef float f32x4  __attribute__((ext_vector_type(4)));   // MFMA C/D

__device__ inline unsigned pack_bf16x2(float a, float b) {
    unsigned ua = __float_as_uint(a);
    ua = (ua + 0x7FFFu + ((ua >> 16) & 1u)) >> 16;       // RNE
    unsigned ub = __float_as_uint(b);
    ub = (ub + 0x7FFFu + ((ub >> 16) & 1u)) >> 16;
    return ua | (ub << 16);
}
__device__ inline ushort bf16_1(float a) {
    unsigned ua = __float_as_uint(a);
    return (ushort)((ua + 0x7FFFu + ((ua >> 16) & 1u)) >> 16);
}
__device__ inline float bf_lo(unsigned u) { return __uint_as_float(u << 16); }
__device__ inline float bf_hi(unsigned u) { return __uint_as_float(u & 0xFFFF0000u); }

// Fused pre-pass: zero cnt, graph bounds, W transpose+cast. Independent jobs.
__global__ void k_prep(int* __restrict__ cnt, int N,
                       const int* __restrict__ batch, int* __restrict__ gb, int G,
                       const float* __restrict__ W0, const float* __restrict__ W1,
                       const float* __restrict__ W2, ushort* __restrict__ WbT) {
    int id = blockIdx.x * blockDim.x + threadIdx.x;
    if (id < N) cnt[id] = 0;
    if (id <= G) {
        int lo = 0, hi = N;
        while (lo < hi) { int mid = (lo + hi) >> 1; if (batch[mid] < id) lo = mid + 1; else hi = mid; }
        gb[id] = lo;
    }
    if (id < 3 * 16384) {
        int l = id >> 14;
        const float* W = (l == 0) ? W0 : ((l == 1) ? W1 : W2);
        int id2 = id & 16383;
        int n = id2 & 127, k = id2 >> 7;
        WbT[l * 16384 + n * 128 + k] = bf16_1(W[k * 128 + n]);
    }
}

// The ONLY atomic kernel: per-edge rank within its destination bucket.
// Also streams the x fp32->bf16 cast (hidden under atomic latency).
__global__ void k_phase1(const int* __restrict__ ei, int* __restrict__ cnt,
                         int* __restrict__ epos, int E,
                         const float4* __restrict__ x4, uint2* __restrict__ xb2,
                         int nCast) {
    int tid = blockIdx.x * blockDim.x + threadIdx.x;
    if (tid < E) {
        int c = ei[E + tid];
        epos[tid] = atomicAdd(&cnt[c], 1);
    }
    int stride = gridDim.x * blockDim.x;
    for (int i = tid; i < nCast; i += stride) {
        float4 f = x4[i];
        uint2 v;
        v.x = pack_bf16x2(f.x, f.y);
        v.y = pack_bf16x2(f.z, f.w);
        xb2[i] = v;
    }
}

// --- multi-block exclusive scan: scan1 (per-block) -> scan2 (block sums) ---
__global__ __launch_bounds__(1024) void k_scan1(const int* __restrict__ cnt,
                                                int* __restrict__ pre,
                                                int* __restrict__ bsum, int n) {
    __shared__ int wsum[16];
    int t = threadIdx.x, lane = t & 63, w = t >> 6;
    int i = blockIdx.x * 1024 + t;
    int v = (i < n) ? cnt[i] : 0;
    int x = v;
#pragma unroll
    for (int off = 1; off < 64; off <<= 1) {
        int y = __shfl_up(x, off, 64);
        if (lane >= off) x += y;
    }
    if (lane == 63) wsum[w] = x;
    __syncthreads();
    int woff = 0, tot = 0;
#pragma unroll
    for (int q = 0; q < 16; q++) { int s = wsum[q]; if (q < w) woff += s; tot += s; }
    if (i < n) pre[i] = woff + x - v;
    if (t == 0) bsum[blockIdx.x] = tot;
}

__global__ __launch_bounds__(128) void k_scan2(int* __restrict__ bsum, int nb,
                                               int* __restrict__ ptrv, int n) {
    __shared__ int ws[2];
    int t = threadIdx.x, lane = t & 63, w = t >> 6;
    int v = (t < nb) ? bsum[t] : 0;
    int x = v;
#pragma unroll
    for (int off = 1; off < 64; off <<= 1) {
        int y = __shfl_up(x, off, 64);
        if (lane >= off) x += y;
    }
    if (lane == 63) ws[w] = x;
    __syncthreads();
    int woff = (w == 1) ? ws[0] : 0;
    int tot = ws[0] + ws[1];
    if (t < nb) bsum[t] = woff + x - v;
    if (t == 0) ptrv[n] = tot;
}

__global__ __launch_bounds__(1024) void k_scan3(const int* __restrict__ pre,
                                                const int* __restrict__ bsum,
                                                int* __restrict__ ptrv, int n) {
    int i = blockIdx.x * 1024 + threadIdx.x;
    if (i >= n) return;
    ptrv[i] = pre[i] + bsum[blockIdx.x];
}

// Scatter edges to CSR slots (plain stores; L2 write-back absorbs them).
__global__ void k_scatter(const int* __restrict__ ei, const float* __restrict__ ew,
                          const int* __restrict__ ptrv, const int* __restrict__ epos,
                          int2* __restrict__ csr, int E) {
    int e = blockIdx.x * blockDim.x + threadIdx.x;
    if (e >= E) return;
    int r = ei[e];
    int c = ei[E + e];
    int2 v; v.x = r; v.y = __float_as_int(ew[e]);
    csr[ptrv[c] + epos[e]] = v;
}

// deg = 1 (self-loop) + sum of bucket weights; dinv = rsqrt(deg).
// Half-wave (32 lanes) per node: coalesced 256B bucket reads + shfl reduce.
__global__ __launch_bounds__(256) void k_degdinv(const int2* __restrict__ csr,
                                                 const int* __restrict__ ptrv,
                                                 float* __restrict__ dinv, int N) {
    int node = blockIdx.x * 8 + (threadIdx.x >> 5);
    int j = threadIdx.x & 31;
    if (node >= N) return;
    int e0 = ptrv[node], e1 = ptrv[node + 1];
    float s = (j == 0) ? 1.0f : 0.0f;
    for (int e = e0 + j; e < e1; e += 32) s += __int_as_float(csr[e].y);
#pragma unroll
    for (int off = 1; off < 32; off <<= 1) s += __shfl_xor(s, off, 64);
    if (j == 0) dinv[node] = rsqrtf(s);
}

// csr.y = dinv[r] * w * dinv[c]. Half-wave per node: coalesced int2 RMW,
// dinv[r] gathers are L2-hot (400 KB array).
__global__ __launch_bounds__(256) void k_norm(int2* __restrict__ csr,
                                              const int* __restrict__ ptrv,
                                              const float* __restrict__ dinv, int N) {
    int node = blockIdx.x * 8 + (threadIdx.x >> 5);
    int j = threadIdx.x & 31;
    if (node >= N) return;
    float dc = dinv[node];
    int e0 = ptrv[node], e1 = ptrv[node + 1];
    for (int e = e0 + j; e < e1; e += 32) {
        int2 m = csr[e];
        m.y = __float_as_int(dinv[m.x] * __int_as_float(m.y) * dc);
        csr[e] = m;
    }
}

// hl = H @ W via v_mfma_f32_16x16x32_bf16. Wave = 32 rows x 128 cols:
// 2 m-strips x 8 n-tiles, 64 MFMAs. A-frag: A[m=lane&15][k=quad*8+j] ->
// 16 B/lane contiguous from bf16-packed H. B-frag: B[k=quad*8+j][n=lane&15]
// -> 16 B/lane contiguous from WbT[n][k]. Epilogue via LDS -> coalesced u32.
__global__ __launch_bounds__(256) void k_gemm_mfma(const unsigned* __restrict__ Hb,
                                                   const ushort* __restrict__ WbT,
                                                   unsigned* __restrict__ O, int M) {
    __shared__ unsigned sOut[4 * 32 * 64];     // 32 KB: 4 waves x 32 rows x 128 bf16
    int lane = threadIdx.x & 63;
    int wv = threadIdx.x >> 6;
    int quad = lane >> 4;
    int mrow = lane & 15;
    int m0 = blockIdx.x * 128 + wv * 32;
    int r0 = m0 + mrow;
    int r1 = r0 + 16;
    int r0c = r0 < M ? r0 : M - 1;             // clamp loads, guard stores
    int r1c = r1 < M ? r1 : M - 1;

    short8 a0[4], a1[4];
#pragma unroll
    for (int s = 0; s < 4; s++) {              // k-step s covers k in [32s,32s+32)
        a0[s] = *(const short8*)(Hb + (size_t)r0c * 64 + s * 16 + quad * 4);
        a1[s] = *(const short8*)(Hb + (size_t)r1c * 64 + s * 16 + quad * 4);
    }
    f32x4 acc0[8], acc1[8];
#pragma unroll
    for (int t = 0; t < 8; t++) {
        acc0[t] = (f32x4){0.f, 0.f, 0.f, 0.f};
        acc1[t] = (f32x4){0.f, 0.f, 0.f, 0.f};
    }
#pragma unroll
    for (int s = 0; s < 4; s++) {
#pragma unroll
        for (int t = 0; t < 8; t++) {
            short8 b = *(const short8*)(WbT + (t * 16 + mrow) * 128 + s * 32 + quad * 8);
            acc0[t] = __builtin_amdgcn_mfma_f32_16x16x32_bf16(a0[s], b, acc0[t], 0, 0, 0);
            acc1[t] = __builtin_amdgcn_mfma_f32_16x16x32_bf16(a1[s], b, acc1[t], 0, 0, 0);
        }
    }
    // C/D layout: col = lane&15, row = quad*4 + reg. Write bf16 to LDS, read
    // back row-major for coalesced u32 global stores.
    ushort* so = (ushort*)(sOut + wv * 32 * 64);
#pragma unroll
    for (int t = 0; t < 8; t++) {
#pragma unroll
        for (int r = 0; r < 4; r++) {
            int lr = quad * 4 + r;
            int c = t * 16 + mrow;
            so[lr * 128 + c] = bf16_1(acc0[t][r]);
            so[(lr + 16) * 128 + c] = bf16_1(acc1[t][r]);
        }
    }
    __syncthreads();
    const unsigned* si = sOut + wv * 32 * 64;
#pragma unroll 8
    for (int r = 0; r < 32; r++) {
        int row = m0 + r;
        if (row < M) O[(size_t)row * 64 + lane] = si[r * 64 + lane];
    }
}

// One wave per node, paired-edge: lanes 0-31 take even edges, lanes 32-63 odd
// edges of the SAME node (no divergence). Each lane loads uint2 (4 features),
// so one load instruction fetches two 256B rows. Cross-half shfl_xor(32)
// merges the partials; half 0 stores.
__global__ __launch_bounds__(256) void k_agg(const unsigned* __restrict__ HL,
                                             const int* __restrict__ ptr,
                                             const int2* __restrict__ csr,
                                             const float* __restrict__ dinv,
                                             const float* __restrict__ bias,
                                             unsigned* __restrict__ Hout, int M) {
    __shared__ int2 sM[4 * 64];
    int node = (int)((blockIdx.x * blockDim.x + threadIdx.x) >> 6);
    if (node >= M) return;
    int lane = threadIdx.x & 63;
    int half = lane >> 5;                 // 0: even edges, 1: odd edges
    int q = lane & 31;                    // features 4q .. 4q+3
    int2* mbase = &sM[(threadIdx.x >> 6) * 64];
    int e0 = ptr[node], e1 = ptr[node + 1];
    int deg = e1 - e0;
    int nbv = deg < 64 ? deg : 64;
    if (lane < nbv) mbase[lane] = csr[e0 + lane];   // one coalesced load
    const uint2* HL2 = (const uint2*)HL;            // row = 32 uint2
    float di = dinv[node];
    float sn = (half == 0) ? di * di : 0.f;         // self-loop on half 0 only
    uint2 us = HL2[(size_t)node * 32 + q];          // both halves same lines
    float a0 = sn * bf_lo(us.x), a1 = sn * bf_hi(us.x);
    float a2 = sn * bf_lo(us.y), a3 = sn * bf_hi(us.y);
    int j = half;
    for (; j + 8 <= nbv; j += 8) {                  // 4 pairs in flight
        int2 m[4]; uint2 u[4];
#pragma unroll
        for (int t = 0; t < 4; t++) m[t] = mbase[j + 2 * t];
#pragma unroll
        for (int t = 0; t < 4; t++) u[t] = HL2[(size_t)m[t].x * 32 + q];
#pragma unroll
        for (int t = 0; t < 4; t++) {
            float nv = __int_as_float(m[t].y);
            a0 += nv * bf_lo(u[t].x); a1 += nv * bf_hi(u[t].x);
            a2 += nv * bf_lo(u[t].y); a3 += nv * bf_hi(u[t].y);
        }
    }
    for (; j < nbv; j += 2) {
        int2 m = mbase[j];
        uint2 u = HL2[(size_t)m.x * 32 + q];
        float nv = __int_as_float(m.y);
        a0 += nv * bf_lo(u.x); a1 += nv * bf_hi(u.x);
        a2 += nv * bf_lo(u.y); a3 += nv * bf_hi(u.y);
    }
    for (int e = e0 + 64 + half; e < e1; e += 2) {  // rare high-degree tail
        int2 m = csr[e];
        uint2 u = HL2[(size_t)m.x * 32 + q];
        float nv = __int_as_float(m.y);
        a0 += nv * bf_lo(u.x); a1 += nv * bf_hi(u.x);
        a2 += nv * bf_lo(u.y); a3 += nv * bf_hi(u.y);
    }
    a0 += __shfl_xor(a0, 32, 64);
    a1 += __shfl_xor(a1, 32, 64);
    a2 += __shfl_xor(a2, 32, 64);
    a3 += __shfl_xor(a3, 32, 64);
    float4 bv = ((const float4*)bias)[q];
    float r0 = fmaxf(a0 + bv.x, 0.f);
    float r1 = fmaxf(a1 + bv.y, 0.f);
    float r2 = fmaxf(a2 + bv.z, 0.f);
    float r3 = fmaxf(a3 + bv.w, 0.f);
    if (half == 0) {
        uint2 pv;
        pv.x = pack_bf16x2(r0, r1);
        pv.y = pack_bf16x2(r2, r3);
        ((uint2*)(Hout + (size_t)node * 64))[q] = pv;
    }
}

// One block per graph: stream the sorted node segment, 4 waves stride it,
// LDS-combine, divide by count, write. No atomics.
__global__ __launch_bounds__(256) void k_pool(const unsigned* __restrict__ HB,
                                              const int* __restrict__ gb,
                                              float* __restrict__ outp) {
    __shared__ float part[4][128];
    int g = blockIdx.x;
    int lane = threadIdx.x & 63, w = threadIdx.x >> 6;
    int s = gb[g], e = gb[g + 1];
    float ax = 0.f, ay = 0.f;
    for (int i = s + w; i < e; i += 4) {
        unsigned u = HB[(size_t)i * 64 + lane];
        ax += bf_lo(u); ay += bf_hi(u);
    }
    part[w][lane * 2] = ax;
    part[w][lane * 2 + 1] = ay;
    __syncthreads();
    if (threadIdx.x < 128) {
        float sum = part[0][threadIdx.x] + part[1][threadIdx.x]
                  + part[2][threadIdx.x] + part[3][threadIdx.x];
        float c = (float)(e - s);
        outp[g * 128 + threadIdx.x] = sum / fmaxf(c, 1.0f);
    }
}

extern "C" void kernel_launch(void* const* d_in, const int* in_sizes, int n_in,
                              void* d_out, int out_size, void* d_ws, size_t ws_size,
                              hipStream_t stream) {
    const float* x     = (const float*)d_in[0];
    const int*   ei    = (const int*)d_in[1];
    const float* ew    = (const float*)d_in[2];
    const int*   batch = (const int*)d_in[3];
    const float* Wt[3] = {(const float*)d_in[4], (const float*)d_in[6], (const float*)d_in[8]};
    const float* bt[3] = {(const float*)d_in[5], (const float*)d_in[7], (const float*)d_in[9]};
    float* out = (float*)d_out;

    const int D = 128;
    const int N = in_sizes[0] / D;       // 100000
    const int E = in_sizes[2];           // 1600000
    const int G = out_size / (3 * D);    // 256

    // workspace carve-up (256 B aligned)
    char* p = (char*)d_ws;
    auto alloc = [&](size_t bytes) {
        void* r = (void*)p;
        p += (bytes + 255) & ~(size_t)255;
        return r;
    };
    int*      cnt    = (int*)alloc((size_t)N * 4);
    int*      ptr    = (int*)alloc((size_t)(N + 1) * 4);
    int*      pre    = (int*)alloc((size_t)N * 4);
    int*      bsum   = (int*)alloc((size_t)128 * 4);
    int*      gb     = (int*)alloc((size_t)(G + 1) * 4);
    float*    dinv   = (float*)alloc((size_t)N * 4);
    ushort*   WbT    = (ushort*)alloc((size_t)3 * 16384 * 2);
    int2*     csr    = (int2*)alloc((size_t)E * 8);
    unsigned* xb     = (unsigned*)alloc((size_t)N * 64 * 4);  // x,  bf16-packed
    unsigned* bufHL  = (unsigned*)alloc((size_t)N * 64 * 4);  // hl, bf16-packed
    unsigned* bufH   = (unsigned*)alloc((size_t)N * 64 * 4);  // h,  bf16-packed
    int*      epos   = (int*)bufH;   // alias: epos dead before bufH first write

    int nb = (N + 1023) / 1024;
    int prepWork = N > 3 * 16384 ? N : 3 * 16384;

    k_prep<<<(prepWork + 255) / 256, 256, 0, stream>>>(cnt, N, batch, gb, G,
                                                       Wt[0], Wt[1], Wt[2], WbT);
    k_phase1<<<(E + 255) / 256, 256, 0, stream>>>(ei, cnt, epos, E,
                                                  (const float4*)x, (uint2*)xb, N * 32);
    k_scan1<<<nb, 1024, 0, stream>>>(cnt, pre, bsum, N);
    k_scan2<<<1, 128, 0, stream>>>(bsum, nb, ptr, N);
    k_scan3<<<nb, 1024, 0, stream>>>(pre, bsum, ptr, N);
    k_scatter<<<(E + 255) / 256, 256, 0, stream>>>(ei, ew, ptr, epos, csr, E);
    k_degdinv<<<(N + 7) / 8, 256, 0, stream>>>(csr, ptr, dinv, N);
    k_norm<<<(N + 7) / 8, 256, 0, stream>>>(csr, ptr, dinv, N);

    for (int l = 0; l < 3; l++) {
        const unsigned* hin = (l == 0) ? xb : bufH;
        k_gemm_mfma<<<(N + 127) / 128, 256, 0, stream>>>(hin, WbT + (size_t)l * 16384,
                                                         bufHL, N);
        k_agg<<<(N + 3) / 4, 256, 0, stream>>>(bufHL, ptr, csr, dinv, bt[l], bufH, N);
        k_pool<<<G, 256, 0, stream>>>(bufH, gb, out + (size_t)l * G * D);
    }
}